// Round 1
// baseline (3181.345 us; speedup 1.0000x reference)
//
#include <hip/hip_runtime.h>
#include <math.h>

// Problem constants
#define Bn 32
#define Cn 256
#define Pn 1024                      // H*W tokens per batch
#define Tn (Bn * Pn * Cn)            // 8,388,608 elements per [b,p,c] tensor

// ws layout (floats): q1 | k | v | q2 | h1 | h12  -> 6 * 32 MiB = 192 MiB
// q1/q2 stored pre-scaled by 1/sqrt(C) = 1/16.

__device__ __forceinline__ void fma4(float4& acc, float s, const float4& v) {
    acc.x = fmaf(s, v.x, acc.x);
    acc.y = fmaf(s, v.y, acc.y);
    acc.z = fmaf(s, v.z, acc.z);
    acc.w = fmaf(s, v.w, acc.w);
}
__device__ __forceinline__ void scale4(float4& a, float s) {
    a.x *= s; a.y *= s; a.z *= s; a.w *= s;
}

// ---------------------------------------------------------------------------
// K1: fused projections. out[b][p][o] = (sum_c in[b][c][p] * w[o][c] + bias[o]) * scale
// grid: (Pn/64, Cn/64, 4*Bn); block: 256
// ---------------------------------------------------------------------------
__global__ __launch_bounds__(256) void proj_kernel(
    const float* __restrict__ x1, const float* __restrict__ x2,
    const float* __restrict__ wq1, const float* __restrict__ bq1,
    const float* __restrict__ wk,  const float* __restrict__ bk,
    const float* __restrict__ wv,  const float* __restrict__ bv,
    const float* __restrict__ wq2, const float* __restrict__ bq2,
    float* __restrict__ ws)
{
    const int z = blockIdx.z;
    const int mat = z >> 5;          // 0:q1 1:k 2:v 3:q2
    const int b = z & 31;
    const float* in;
    const float* w;
    const float* bias;
    float* out;
    float scale;
    switch (mat) {
        case 0:  in = x1; w = wq1; bias = bq1; out = ws;               scale = 0.0625f; break;
        case 1:  in = x1; w = wk;  bias = bk;  out = ws + 1*(size_t)Tn; scale = 1.0f;   break;
        case 2:  in = x1; w = wv;  bias = bv;  out = ws + 2*(size_t)Tn; scale = 1.0f;   break;
        default: in = x2; w = wq2; bias = bq2; out = ws + 3*(size_t)Tn; scale = 0.0625f; break;
    }
    const int p0 = blockIdx.x * 64;
    const int o0 = blockIdx.y * 64;
    __shared__ float Xs[16][64];     // [c][p]
    __shared__ float Ws[16][68];     // [c][o], padded
    const int tid = threadIdx.x;
    const int p_base = (tid & 15) * 4;
    const int o_base = (tid >> 4) * 4;
    float acc[4][4] = {};

    for (int c0 = 0; c0 < Cn; c0 += 16) {
        #pragma unroll
        for (int i = 0; i < 4; i++) {
            int e = tid + i * 256;
            int cc = e >> 6, pp = e & 63;
            Xs[cc][pp] = in[((size_t)(b * Cn + c0 + cc)) * Pn + p0 + pp];
        }
        #pragma unroll
        for (int i = 0; i < 4; i++) {
            int e = tid + i * 256;
            int oo = e >> 4, cc = e & 15;
            Ws[cc][oo] = w[(o0 + oo) * Cn + c0 + cc];
        }
        __syncthreads();
        #pragma unroll
        for (int cc = 0; cc < 16; cc++) {
            float4 a  = *(const float4*)&Xs[cc][p_base];
            float4 bb = *(const float4*)&Ws[cc][o_base];
            float av[4] = {a.x, a.y, a.z, a.w};
            float bv4[4] = {bb.x, bb.y, bb.z, bb.w};
            #pragma unroll
            for (int i = 0; i < 4; i++)
                #pragma unroll
                for (int j = 0; j < 4; j++)
                    acc[i][j] = fmaf(av[i], bv4[j], acc[i][j]);
        }
        __syncthreads();
    }
    #pragma unroll
    for (int i = 0; i < 4; i++) {
        int p = p0 + p_base + i;
        float4 o4;
        o4.x = (acc[i][0] + bias[o0 + o_base + 0]) * scale;
        o4.y = (acc[i][1] + bias[o0 + o_base + 1]) * scale;
        o4.z = (acc[i][2] + bias[o0 + o_base + 2]) * scale;
        o4.w = (acc[i][3] + bias[o0 + o_base + 3]) * scale;
        *(float4*)&out[((size_t)(b * Pn + p)) * Cn + o0 + o_base] = o4;
    }
}

// ---------------------------------------------------------------------------
// K2: fused attention, online softmax for BOTH softmax(w1) and softmax(w1+w2).
// grid: (Pn/16, Bn); block: 128 (2 waves)
// ---------------------------------------------------------------------------
#define QT 16
#define KT 16

__global__ __launch_bounds__(128) void attn_kernel(float* __restrict__ ws)
{
    const float* Q1 = ws;
    const float* Km = ws + 1 * (size_t)Tn;
    const float* Vm = ws + 2 * (size_t)Tn;
    const float* Q2 = ws + 3 * (size_t)Tn;
    float* H1  = ws + 4 * (size_t)Tn;
    float* H12 = ws + 5 * (size_t)Tn;

    const int b  = blockIdx.y;
    const int q0 = blockIdx.x * QT;
    const int tid  = threadIdx.x;
    const int lane = tid & 63;
    const int wv_  = tid >> 6;        // wave id 0..1

    __shared__ float Q1s[QT][Cn];
    __shared__ float Q2s[QT][Cn];
    __shared__ float KVs[KT][Cn];
    __shared__ float S1[QT][KT + 1];
    __shared__ float S2[QT][KT + 1];
    __shared__ float m1s[QT], l1s[QT], m12s[QT], l12s[QT], a1s[QT], a12s[QT];

    // load Q tiles (pre-scaled): 1024 float4 / 128 threads = 8 each
    #pragma unroll
    for (int i = 0; i < 8; i++) {
        int idx4 = tid + i * 128;
        int q = idx4 >> 6;
        int c = (idx4 & 63) * 4;
        size_t g = ((size_t)(b * Pn + q0 + q)) * Cn + c;
        *(float4*)&Q1s[q][c] = *(const float4*)&Q1[g];
        *(float4*)&Q2s[q][c] = *(const float4*)&Q2[g];
    }
    if (tid < QT) {
        m1s[tid] = -1e30f; l1s[tid] = 0.f;
        m12s[tid] = -1e30f; l12s[tid] = 0.f;
    }

    // score-phase mapping: 16 micro-tiles (4q x 4k), 8-way c-split in-wave
    const int tile = wv_ * 8 + (lane & 7);   // 0..15
    const int qg = tile >> 2;                // 0..3
    const int kg = tile & 3;                 // 0..3
    const int ct = lane >> 3;                // 0..7

    // PV mapping: thread -> q rows {qp*2, qp*2+1}, c block cg*16..+15
    const int qp = tid >> 4;                 // 0..7
    const int cg = tid & 15;                 // 0..15
    float4 h1a[4] = {}, h1b[4] = {}, h12a[4] = {}, h12b[4] = {};

    for (int kt = 0; kt < Pn / KT; kt++) {
        const int k0 = kt * KT;
        __syncthreads();                     // (A) previous PV done with KVs/S
        #pragma unroll
        for (int i = 0; i < 8; i++) {
            int idx4 = tid + i * 128;
            int r = idx4 >> 6;
            int c = (idx4 & 63) * 4;
            *(float4*)&KVs[r][c] = *(const float4*)&Km[((size_t)(b * Pn + k0 + r)) * Cn + c];
        }
        __syncthreads();                     // (B) K tile visible

        // ---- scores ----
        float s1[4][4] = {}, s2[4][4] = {};
        #pragma unroll
        for (int m = 0; m < 8; m++) {
            int c = ct * 4 + m * 32;         // interleaved chunks: bank-friendly
            float4 kv[4], q1v[4], q2v[4];
            #pragma unroll
            for (int j = 0; j < 4; j++) kv[j] = *(const float4*)&KVs[kg * 4 + j][c];
            #pragma unroll
            for (int i = 0; i < 4; i++) {
                q1v[i] = *(const float4*)&Q1s[qg * 4 + i][c];
                q2v[i] = *(const float4*)&Q2s[qg * 4 + i][c];
            }
            #pragma unroll
            for (int i = 0; i < 4; i++)
                #pragma unroll
                for (int j = 0; j < 4; j++) {
                    s1[i][j] += q1v[i].x * kv[j].x + q1v[i].y * kv[j].y
                              + q1v[i].z * kv[j].z + q1v[i].w * kv[j].w;
                    s2[i][j] += q2v[i].x * kv[j].x + q2v[i].y * kv[j].y
                              + q2v[i].z * kv[j].z + q2v[i].w * kv[j].w;
                }
        }
        // reduce across ct (lane bits 3..5), write tiles from ct==0 lanes
        #pragma unroll
        for (int i = 0; i < 4; i++)
            #pragma unroll
            for (int j = 0; j < 4; j++) {
                float v1 = s1[i][j], v2 = s2[i][j];
                v1 += __shfl_xor(v1, 8);  v2 += __shfl_xor(v2, 8);
                v1 += __shfl_xor(v1, 16); v2 += __shfl_xor(v2, 16);
                v1 += __shfl_xor(v1, 32); v2 += __shfl_xor(v2, 32);
                if (ct == 0) {
                    S1[qg * 4 + i][kg * 4 + j] = v1;
                    S2[qg * 4 + i][kg * 4 + j] = v2;
                }
            }
        __syncthreads();                     // (C) raw scores visible; KVs reads done

        // ---- online softmax for both a1=softmax(S1) and a12=softmax(S1+S2) ----
        {
            const int row = tid >> 3, seg = tid & 7;
            float sv1[2], sv12[2];
            #pragma unroll
            for (int jj = 0; jj < 2; jj++) {
                float a = S1[row][seg * 2 + jj];
                float c2 = S2[row][seg * 2 + jj];
                sv1[jj] = a;
                sv12[jj] = a + c2;
            }
            float mx1 = fmaxf(sv1[0], sv1[1]);
            float mx12 = fmaxf(sv12[0], sv12[1]);
            #pragma unroll
            for (int d = 1; d <= 4; d <<= 1) {
                mx1 = fmaxf(mx1, __shfl_xor(mx1, d));
                mx12 = fmaxf(mx12, __shfl_xor(mx12, d));
            }
            float om1 = m1s[row], om12 = m12s[row];
            float nm1 = fmaxf(om1, mx1), nm12 = fmaxf(om12, mx12);
            float sum1 = 0.f, sum12 = 0.f;
            #pragma unroll
            for (int jj = 0; jj < 2; jj++) {
                float p1 = __expf(sv1[jj] - nm1);
                float p12 = __expf(sv12[jj] - nm12);
                S1[row][seg * 2 + jj] = p1;   // overwrite scores with probs
                S2[row][seg * 2 + jj] = p12;
                sum1 += p1; sum12 += p12;
            }
            #pragma unroll
            for (int d = 1; d <= 4; d <<= 1) {
                sum1 += __shfl_xor(sum1, d);
                sum12 += __shfl_xor(sum12, d);
            }
            if (seg == 0) {
                float al1 = __expf(om1 - nm1);
                float al12 = __expf(om12 - nm12);
                l1s[row] = l1s[row] * al1 + sum1;   m1s[row] = nm1;   a1s[row] = al1;
                l12s[row] = l12s[row] * al12 + sum12; m12s[row] = nm12; a12s[row] = al12;
            }
        }
        // load V tile (overwrites KVs; K reads finished at (C))
        #pragma unroll
        for (int i = 0; i < 8; i++) {
            int idx4 = tid + i * 128;
            int r = idx4 >> 6;
            int c = (idx4 & 63) * 4;
            *(float4*)&KVs[r][c] = *(const float4*)&Vm[((size_t)(b * Pn + k0 + r)) * Cn + c];
        }
        __syncthreads();                     // (D) probs + alphas + V visible

        // ---- PV accumulate with rescale ----
        {
            const float al1a = a1s[qp * 2],  al1b = a1s[qp * 2 + 1];
            const float al2a = a12s[qp * 2], al2b = a12s[qp * 2 + 1];
            #pragma unroll
            for (int m = 0; m < 4; m++) {
                scale4(h1a[m], al1a); scale4(h1b[m], al1b);
                scale4(h12a[m], al2a); scale4(h12b[m], al2b);
            }
            #pragma unroll 4
            for (int k = 0; k < KT; k++) {
                float p1a = S1[qp * 2][k],  p1b = S1[qp * 2 + 1][k];
                float p2a = S2[qp * 2][k],  p2b = S2[qp * 2 + 1][k];
                #pragma unroll
                for (int m = 0; m < 4; m++) {
                    float4 v = *(const float4*)&KVs[k][cg * 16 + m * 4];
                    fma4(h1a[m], p1a, v);  fma4(h1b[m], p1b, v);
                    fma4(h12a[m], p2a, v); fma4(h12b[m], p2b, v);
                }
            }
        }
    }

    // epilogue: normalize and store
    const float i1a = 1.f / l1s[qp * 2],  i1b = 1.f / l1s[qp * 2 + 1];
    const float i2a = 1.f / l12s[qp * 2], i2b = 1.f / l12s[qp * 2 + 1];
    size_t ga = ((size_t)(b * Pn + q0 + qp * 2)) * Cn + cg * 16;
    size_t gb = ga + Cn;
    #pragma unroll
    for (int m = 0; m < 4; m++) {
        float4 r;
        r = h1a[m];  scale4(r, i1a); *(float4*)&H1[ga + m * 4] = r;
        r = h1b[m];  scale4(r, i1b); *(float4*)&H1[gb + m * 4] = r;
        r = h12a[m]; scale4(r, i2a); *(float4*)&H12[ga + m * 4] = r;
        r = h12b[m]; scale4(r, i2b); *(float4*)&H12[gb + m * 4] = r;
    }
}

// ---------------------------------------------------------------------------
// K3: out[b][o][p] = x1[b][o][p] + bias[o] + sum_c h[b][p][c] * w[o][c]
// grid: (Pn/64, Cn/64, 2*Bn); block: 256
// ---------------------------------------------------------------------------
__global__ __launch_bounds__(256) void outproj_kernel(
    const float* __restrict__ x1,
    const float* __restrict__ wps, const float* __restrict__ bps,
    const float* __restrict__ wpc, const float* __restrict__ bpc,
    const float* __restrict__ ws, float* __restrict__ outp)
{
    const int z = blockIdx.z;
    const int mat = z >> 5;          // 0: h1->wps->out[0:Tn), 1: h12->wpc->out[Tn:2Tn)
    const int b = z & 31;
    const float* h = ws + (size_t)(4 + mat) * Tn;
    const float* w = mat ? wpc : wps;
    const float* bias = mat ? bpc : bps;
    float* out = outp + (size_t)mat * Tn;

    const int p0 = blockIdx.x * 64;
    const int o0 = blockIdx.y * 64;
    __shared__ float Hs[16][68];     // [c][p]
    __shared__ float Ws[16][68];     // [c][o]
    const int tid = threadIdx.x;
    const int p_base = (tid & 15) * 4;
    const int o_base = (tid >> 4) * 4;
    float acc[4][4] = {};

    for (int c0 = 0; c0 < Cn; c0 += 16) {
        {
            int e = tid * 4;                 // 1024 elements, 4 contiguous c each
            int pp = e >> 4, cc = e & 15;
            float4 hv = *(const float4*)&h[((size_t)(b * Pn + p0 + pp)) * Cn + c0 + cc];
            Hs[cc + 0][pp] = hv.x; Hs[cc + 1][pp] = hv.y;
            Hs[cc + 2][pp] = hv.z; Hs[cc + 3][pp] = hv.w;
        }
        #pragma unroll
        for (int i = 0; i < 4; i++) {
            int e = tid + i * 256;
            int oo = e >> 4, cc = e & 15;
            Ws[cc][oo] = w[(o0 + oo) * Cn + c0 + cc];
        }
        __syncthreads();
        #pragma unroll
        for (int cc = 0; cc < 16; cc++) {
            float4 a  = *(const float4*)&Hs[cc][p_base];
            float4 bb = *(const float4*)&Ws[cc][o_base];
            float av[4] = {a.x, a.y, a.z, a.w};
            float bv4[4] = {bb.x, bb.y, bb.z, bb.w};
            #pragma unroll
            for (int i = 0; i < 4; i++)
                #pragma unroll
                for (int j = 0; j < 4; j++)
                    acc[i][j] = fmaf(av[i], bv4[j], acc[i][j]);
        }
        __syncthreads();
    }
    #pragma unroll
    for (int j = 0; j < 4; j++) {
        int oc = o0 + o_base + j;
        float bv = bias[oc];
        size_t base = ((size_t)(b * Cn + oc)) * Pn + p0 + p_base;
        float4 xv = *(const float4*)&x1[base];
        float4 r;
        r.x = xv.x + bv + acc[0][j];
        r.y = xv.y + bv + acc[1][j];
        r.z = xv.z + bv + acc[2][j];
        r.w = xv.w + bv + acc[3][j];
        *(float4*)&out[base] = r;
    }
}

// ---------------------------------------------------------------------------
extern "C" void kernel_launch(void* const* d_in, const int* in_sizes, int n_in,
                              void* d_out, int out_size, void* d_ws, size_t ws_size,
                              hipStream_t stream)
{
    const float* x1  = (const float*)d_in[0];
    const float* x2  = (const float*)d_in[1];
    const float* wq1 = (const float*)d_in[2];
    const float* bq1 = (const float*)d_in[3];
    const float* wk  = (const float*)d_in[4];
    const float* bk  = (const float*)d_in[5];
    const float* wv  = (const float*)d_in[6];
    const float* bv  = (const float*)d_in[7];
    const float* wq2 = (const float*)d_in[8];
    const float* bq2 = (const float*)d_in[9];
    const float* wps = (const float*)d_in[10];
    const float* bps = (const float*)d_in[11];
    const float* wpc = (const float*)d_in[12];
    const float* bpc = (const float*)d_in[13];
    float* out = (float*)d_out;
    float* ws  = (float*)d_ws;
    // needs 6 * Tn * 4 = 192 MiB of workspace

    proj_kernel<<<dim3(Pn / 64, Cn / 64, 4 * Bn), 256, 0, stream>>>(
        x1, x2, wq1, bq1, wk, bk, wv, bv, wq2, bq2, ws);
    attn_kernel<<<dim3(Pn / QT, Bn), 128, 0, stream>>>(ws);
    outproj_kernel<<<dim3(Pn / 64, Cn / 64, 2 * Bn), 256, 0, stream>>>(
        x1, wps, bps, wpc, bpc, ws, out);
}

// Round 2
// 700.806 us; speedup vs baseline: 4.5396x; 4.5396x over previous
//
#include <hip/hip_runtime.h>
#include <math.h>

#define Bn 32
#define Cn 256
#define Pn 1024                       // H*W tokens per batch
#define Tn (Bn * Pn * Cn)             // 8,388,608 elems per [b,p,c] tensor

typedef __bf16 bf16x8 __attribute__((ext_vector_type(8)));
typedef float  f32x4  __attribute__((ext_vector_type(4)));
typedef unsigned short u16;
typedef u16 u16x8 __attribute__((ext_vector_type(8)));

// fp32 -> bf16 round-to-nearest-even (finite inputs)
__device__ __forceinline__ u16 f2b(float f) {
    union { float f; unsigned u; } c; c.f = f;
    return (u16)((c.u + 0x7FFFu + ((c.u >> 16) & 1u)) >> 16);
}

// ws layout (u16 units): q1 bf16 | k bf16 | vt bf16 [b][c][p] | q2 bf16 | then
// fp32 h1 | fp32 h12 at byte offset 4*Tn*2.  Total 128 MiB.

// ---------------------------------------------------------------------------
// K1: fused projections -> bf16.  out[b][p][o] = (sum_c in[b][c][p]*w[o][c]+bias[o])*scale
// mat 2 (V) is stored transposed: vt[b][o][p].
// grid: (Pn/64, Cn/64, 4*Bn); block 256
// ---------------------------------------------------------------------------
__global__ __launch_bounds__(256) void proj_kernel(
    const float* __restrict__ x1, const float* __restrict__ x2,
    const float* __restrict__ wq1, const float* __restrict__ bq1,
    const float* __restrict__ wk,  const float* __restrict__ bk,
    const float* __restrict__ wv,  const float* __restrict__ bv,
    const float* __restrict__ wq2, const float* __restrict__ bq2,
    u16* __restrict__ ws16)
{
    const int z = blockIdx.z;
    const int mat = z >> 5;          // 0:q1 1:k 2:v(transposed) 3:q2
    const int b = z & 31;
    const float* in;
    const float* w;
    const float* bias;
    u16* outb;
    float scale;
    switch (mat) {
        case 0:  in = x1; w = wq1; bias = bq1; outb = ws16;                 scale = 0.0625f; break;
        case 1:  in = x1; w = wk;  bias = bk;  outb = ws16 + 1*(size_t)Tn;  scale = 1.0f;    break;
        case 2:  in = x1; w = wv;  bias = bv;  outb = ws16 + 2*(size_t)Tn;  scale = 1.0f;    break;
        default: in = x2; w = wq2; bias = bq2; outb = ws16 + 3*(size_t)Tn;  scale = 0.0625f; break;
    }
    const int p0 = blockIdx.x * 64;
    const int o0 = blockIdx.y * 64;
    __shared__ float Xs[16][64];
    __shared__ float Wsh[16][68];
    const int tid = threadIdx.x;
    const int p_base = (tid & 15) * 4;
    const int o_base = (tid >> 4) * 4;
    float acc[4][4] = {};

    for (int c0 = 0; c0 < Cn; c0 += 16) {
        #pragma unroll
        for (int i = 0; i < 4; i++) {
            int e = tid + i * 256;
            int cc = e >> 6, pp = e & 63;
            Xs[cc][pp] = in[((size_t)(b * Cn + c0 + cc)) * Pn + p0 + pp];
        }
        #pragma unroll
        for (int i = 0; i < 4; i++) {
            int e = tid + i * 256;
            int oo = e >> 4, cc = e & 15;
            Wsh[cc][oo] = w[(o0 + oo) * Cn + c0 + cc];
        }
        __syncthreads();
        #pragma unroll
        for (int cc = 0; cc < 16; cc++) {
            float4 a  = *(const float4*)&Xs[cc][p_base];
            float4 bb = *(const float4*)&Wsh[cc][o_base];
            float av[4] = {a.x, a.y, a.z, a.w};
            float bv4[4] = {bb.x, bb.y, bb.z, bb.w};
            #pragma unroll
            for (int i = 0; i < 4; i++)
                #pragma unroll
                for (int j = 0; j < 4; j++)
                    acc[i][j] = fmaf(av[i], bv4[j], acc[i][j]);
        }
        __syncthreads();
    }
    if (mat != 2) {
        #pragma unroll
        for (int i = 0; i < 4; i++) {
            int p = p0 + p_base + i;
            ushort4 o4 = make_ushort4(
                f2b((acc[i][0] + bias[o0 + o_base + 0]) * scale),
                f2b((acc[i][1] + bias[o0 + o_base + 1]) * scale),
                f2b((acc[i][2] + bias[o0 + o_base + 2]) * scale),
                f2b((acc[i][3] + bias[o0 + o_base + 3]) * scale));
            *(ushort4*)&outb[((size_t)(b * Pn + p)) * Cn + o0 + o_base] = o4;
        }
    } else {
        #pragma unroll
        for (int j = 0; j < 4; j++) {
            int oc = o0 + o_base + j;
            float bvs = bias[oc];
            ushort4 o4 = make_ushort4(
                f2b(acc[0][j] + bvs), f2b(acc[1][j] + bvs),
                f2b(acc[2][j] + bvs), f2b(acc[3][j] + bvs));
            *(ushort4*)&outb[((size_t)(b * Cn + oc)) * Pn + p0 + p_base] = o4;
        }
    }
}

// ---------------------------------------------------------------------------
// K2: bf16-MFMA flash attention, dual-path (softmax(S1) and softmax(S1+S2)).
// block = 256 (4 waves): wave = (path, qsub); 32 q-rows per block, 32 k per iter.
// grid: (Pn/32, Bn)
// ---------------------------------------------------------------------------
__global__ __launch_bounds__(256) void attn_kernel(
    const u16* __restrict__ ws16, float* __restrict__ h1, float* __restrict__ h12)
{
    const u16* Q1 = ws16;
    const u16* Kg = ws16 + 1 * (size_t)Tn;
    const u16* Vt = ws16 + 2 * (size_t)Tn;
    const u16* Q2 = ws16 + 3 * (size_t)Tn;

    __shared__ __align__(16) u16  Klds[32 * 256];   // [tok][c], groups swizzled by tok&7
    __shared__ __align__(16) u16  Vtlds[256 * 32];  // [c][tok], groups swizzled by c&3
    __shared__ float S1lds[32 * 33];                // fp32 S1 exchange
    __shared__ __align__(16) u16  Plds[2 * 32 * 40];// bf16 P, row pad 40

    const int b    = blockIdx.y;
    const int q0   = blockIdx.x * 32;
    const int tid  = threadIdx.x;
    const int wv   = tid >> 6;
    const int path = wv >> 1;       // 0 -> H1 (S1), 1 -> H12 (S1+S2)
    const int qsub = wv & 1;
    const int lane = tid & 63;
    const int ln   = lane & 15;
    const int quad = lane >> 4;
    const int pbase = path * (32 * 40);

    // resident A-fragments for this wave's 16 q rows (whole C=256)
    const u16* Qg = path ? Q2 : Q1;
    const size_t qrow = (size_t)(b * Pn + q0 + qsub * 16 + ln) * Cn;
    bf16x8 qa[8];
    #pragma unroll
    for (int ch = 0; ch < 8; ch++)
        qa[ch] = *(const bf16x8*)&Qg[qrow + ch * 32 + quad * 8];

    f32x4 acc[16];
    #pragma unroll
    for (int t = 0; t < 16; t++) acc[t] = (f32x4){0.f, 0.f, 0.f, 0.f};
    float mrow[4] = {-1e30f, -1e30f, -1e30f, -1e30f};
    float lrow[4] = {0.f, 0.f, 0.f, 0.f};

    for (int kt = 0; kt < 32; kt++) {
        const int k0 = kt * 32;
        __syncthreads();   // (A) previous PV done; LDS reusable

        // stage K tile [32][256]
        {
            const int tok = tid >> 3, gi = tid & 7;
            const size_t grow = (size_t)(b * Pn + k0 + tok) * Cn;
            #pragma unroll
            for (int i = 0; i < 4; i++) {
                int glog = 8 * i + (gi ^ (tok & 7));
                *(u16x8*)&Klds[tok * 256 + (8 * i + gi) * 8] =
                    *(const u16x8*)&Kg[grow + glog * 8];
            }
        }
        // stage Vt tile [256][32]
        {
            const int cb = tid >> 2, g = tid & 3;
            #pragma unroll
            for (int i = 0; i < 4; i++) {
                int cl = cb + 64 * i;
                int gp = g ^ (cl & 3);
                *(u16x8*)&Vtlds[cl * 32 + gp * 8] =
                    *(const u16x8*)&Vt[((size_t)(b * Cn + cl)) * Pn + k0 + g * 8];
            }
        }
        __syncthreads();   // (B) tiles visible

        // scores: S[16 q][32 k], k in two 16-wide subtiles
        float sv[2][4];
        #pragma unroll
        for (int st = 0; st < 2; st++) {
            f32x4 s = (f32x4){0.f, 0.f, 0.f, 0.f};
            #pragma unroll
            for (int ch = 0; ch < 8; ch++) {
                bf16x8 kb = *(const bf16x8*)
                    &Klds[(st * 16 + ln) * 256 + (((ch * 4 + quad) ^ (ln & 7))) * 8];
                s = __builtin_amdgcn_mfma_f32_16x16x32_bf16(qa[ch], kb, s, 0, 0, 0);
            }
            #pragma unroll
            for (int r = 0; r < 4; r++) sv[st][r] = s[r];
        }
        if (path == 0) {
            #pragma unroll
            for (int st = 0; st < 2; st++)
                #pragma unroll
                for (int r = 0; r < 4; r++)
                    S1lds[(qsub * 16 + quad * 4 + r) * 33 + st * 16 + ln] = sv[st][r];
        }
        __syncthreads();   // (C) S1 exchange
        if (path == 1) {
            #pragma unroll
            for (int st = 0; st < 2; st++)
                #pragma unroll
                for (int r = 0; r < 4; r++)
                    sv[st][r] += S1lds[(qsub * 16 + quad * 4 + r) * 33 + st * 16 + ln];
        }

        // online softmax (rows live on (quad, r); 16 k-lanes per row)
        #pragma unroll
        for (int r = 0; r < 4; r++) {
            float mx = fmaxf(sv[0][r], sv[1][r]);
            mx = fmaxf(mx, __shfl_xor(mx, 1));
            mx = fmaxf(mx, __shfl_xor(mx, 2));
            mx = fmaxf(mx, __shfl_xor(mx, 4));
            mx = fmaxf(mx, __shfl_xor(mx, 8));
            float mn = fmaxf(mrow[r], mx);
            float al = __expf(mrow[r] - mn);
            float p0 = __expf(sv[0][r] - mn);
            float p1 = __expf(sv[1][r] - mn);
            float rs = p0 + p1;
            rs += __shfl_xor(rs, 1);
            rs += __shfl_xor(rs, 2);
            rs += __shfl_xor(rs, 4);
            rs += __shfl_xor(rs, 8);
            lrow[r] = lrow[r] * al + rs;
            mrow[r] = mn;
            #pragma unroll
            for (int t = 0; t < 16; t++) acc[t][r] *= al;
            int q_l = qsub * 16 + quad * 4 + r;
            Plds[pbase + q_l * 40 + ln]      = f2b(p0);
            Plds[pbase + q_l * 40 + 16 + ln] = f2b(p1);
        }

        // PV: A = P (own rows, LDS layout transform), B = Vt tiles
        bf16x8 pa = *(const bf16x8*)&Plds[pbase + (qsub * 16 + ln) * 40 + quad * 8];
        #pragma unroll
        for (int t = 0; t < 16; t++) {
            bf16x8 vb = *(const bf16x8*)
                &Vtlds[(t * 16 + ln) * 32 + (quad ^ (ln & 3)) * 8];
            acc[t] = __builtin_amdgcn_mfma_f32_16x16x32_bf16(pa, vb, acc[t], 0, 0, 0);
        }
    }

    float* H = path ? h12 : h1;
    #pragma unroll
    for (int r = 0; r < 4; r++) {
        float inv = 1.f / lrow[r];
        size_t rowb = (size_t)(b * Pn + q0 + qsub * 16 + quad * 4 + r) * Cn;
        #pragma unroll
        for (int t = 0; t < 16; t++)
            H[rowb + t * 16 + ln] = acc[t][r] * inv;
    }
}

// ---------------------------------------------------------------------------
// K3: out[b][o][p] = x1[b][o][p] + bias[o] + sum_c h[b][p][c] * w[o][c]
// grid: (Pn/64, Cn/64, 2*Bn); block 256
// ---------------------------------------------------------------------------
__global__ __launch_bounds__(256) void outproj_kernel(
    const float* __restrict__ x1,
    const float* __restrict__ wps, const float* __restrict__ bps,
    const float* __restrict__ wpc, const float* __restrict__ bpc,
    const float* __restrict__ h1, const float* __restrict__ h12,
    float* __restrict__ outp)
{
    const int z = blockIdx.z;
    const int mat = z >> 5;
    const int b = z & 31;
    const float* h = mat ? h12 : h1;
    const float* w = mat ? wpc : wps;
    const float* bias = mat ? bpc : bps;
    float* out = outp + (size_t)mat * Tn;

    const int p0 = blockIdx.x * 64;
    const int o0 = blockIdx.y * 64;
    __shared__ float Hs[16][68];
    __shared__ float Wsh[16][68];
    const int tid = threadIdx.x;
    const int p_base = (tid & 15) * 4;
    const int o_base = (tid >> 4) * 4;
    float acc[4][4] = {};

    for (int c0 = 0; c0 < Cn; c0 += 16) {
        {
            int e = tid * 4;
            int pp = e >> 4, cc = e & 15;
            float4 hv = *(const float4*)&h[((size_t)(b * Pn + p0 + pp)) * Cn + c0 + cc];
            Hs[cc + 0][pp] = hv.x; Hs[cc + 1][pp] = hv.y;
            Hs[cc + 2][pp] = hv.z; Hs[cc + 3][pp] = hv.w;
        }
        #pragma unroll
        for (int i = 0; i < 4; i++) {
            int e = tid + i * 256;
            int oo = e >> 4, cc = e & 15;
            Wsh[cc][oo] = w[(o0 + oo) * Cn + c0 + cc];
        }
        __syncthreads();
        #pragma unroll
        for (int cc = 0; cc < 16; cc++) {
            float4 a  = *(const float4*)&Hs[cc][p_base];
            float4 bb = *(const float4*)&Wsh[cc][o_base];
            float av[4] = {a.x, a.y, a.z, a.w};
            float bv4[4] = {bb.x, bb.y, bb.z, bb.w};
            #pragma unroll
            for (int i = 0; i < 4; i++)
                #pragma unroll
                for (int j = 0; j < 4; j++)
                    acc[i][j] = fmaf(av[i], bv4[j], acc[i][j]);
        }
        __syncthreads();
    }
    #pragma unroll
    for (int j = 0; j < 4; j++) {
        int oc = o0 + o_base + j;
        float bvs = bias[oc];
        size_t base = ((size_t)(b * Cn + oc)) * Pn + p0 + p_base;
        float4 xv = *(const float4*)&x1[base];
        float4 r;
        r.x = xv.x + bvs + acc[0][j];
        r.y = xv.y + bvs + acc[1][j];
        r.z = xv.z + bvs + acc[2][j];
        r.w = xv.w + bvs + acc[3][j];
        *(float4*)&out[base] = r;
    }
}

// ---------------------------------------------------------------------------
extern "C" void kernel_launch(void* const* d_in, const int* in_sizes, int n_in,
                              void* d_out, int out_size, void* d_ws, size_t ws_size,
                              hipStream_t stream)
{
    const float* x1  = (const float*)d_in[0];
    const float* x2  = (const float*)d_in[1];
    const float* wq1 = (const float*)d_in[2];
    const float* bq1 = (const float*)d_in[3];
    const float* wk  = (const float*)d_in[4];
    const float* bk  = (const float*)d_in[5];
    const float* wv  = (const float*)d_in[6];
    const float* bv  = (const float*)d_in[7];
    const float* wq2 = (const float*)d_in[8];
    const float* bq2 = (const float*)d_in[9];
    const float* wps = (const float*)d_in[10];
    const float* bps = (const float*)d_in[11];
    const float* wpc = (const float*)d_in[12];
    const float* bpc = (const float*)d_in[13];
    float* out = (float*)d_out;

    u16*   ws16 = (u16*)d_ws;
    float* h1   = (float*)(ws16 + (size_t)4 * Tn);   // byte off 64 MiB
    float* h12  = h1 + (size_t)Tn;                   // total 128 MiB

    proj_kernel<<<dim3(Pn / 64, Cn / 64, 4 * Bn), 256, 0, stream>>>(
        x1, x2, wq1, bq1, wk, bk, wv, bv, wq2, bq2, ws16);
    attn_kernel<<<dim3(Pn / 32, Bn), 256, 0, stream>>>(ws16, h1, h12);
    outproj_kernel<<<dim3(Pn / 64, Cn / 64, 2 * Bn), 256, 0, stream>>>(
        x1, wps, bps, wpc, bpc, h1, h12, out);
}

// Round 3
// 403.388 us; speedup vs baseline: 7.8866x; 1.7373x over previous
//
#include <hip/hip_runtime.h>
#include <math.h>

#define Bn 32
#define Cn 256
#define Pn 1024                       // H*W tokens per batch
#define Tn (Bn * Pn * Cn)             // 8,388,608 elems per [b,p,c] tensor

typedef __bf16 bf16x8 __attribute__((ext_vector_type(8)));
typedef float  f32x4  __attribute__((ext_vector_type(4)));
typedef unsigned short u16;
typedef u16 u16x8 __attribute__((ext_vector_type(8)));

// ws layout in u16 units (total ~129 MiB):
#define XT1o ((size_t)0)              // xt of x1: [b][p][c] bf16
#define XT2o ((size_t)1 * Tn)         // xt of x2
#define Q1o  ((size_t)2 * Tn)         // q1 bf16 [b][p][c], pre-scaled 1/16
#define Ko   ((size_t)3 * Tn)         // k  bf16 [b][p][c]
#define VTo  ((size_t)4 * Tn)         // vt bf16 [b][c][p]
#define Q2o  ((size_t)5 * Tn)         // q2 bf16 [b][p][c], pre-scaled 1/16
#define H1o  ((size_t)6 * Tn)         // h1 bf16 [b][p][c]
#define H12o ((size_t)7 * Tn)         // h12 bf16 [b][p][c]
#define WBo  ((size_t)8 * Tn)         // 6 weight mats bf16 [o][c]: q1,k,v,q2,ps,pc

__device__ __forceinline__ u16 f2b(float f) {
    union { float f; unsigned u; } c; c.f = f;
    return (u16)((c.u + 0x7FFFu + ((c.u >> 16) & 1u)) >> 16);
}

// ---------------------------------------------------------------------------
// cvt: x1,x2 [b][c][p] fp32 -> xt [b][p][c] bf16 ; weights fp32 -> bf16.
// grid (16, 4, 70); block 256.  z<64: transpose tiles; z>=64: weight convert.
// ---------------------------------------------------------------------------
__global__ __launch_bounds__(256) void cvt_kernel(
    const float* __restrict__ x1, const float* __restrict__ x2,
    const float* __restrict__ wq1, const float* __restrict__ wk,
    const float* __restrict__ wv,  const float* __restrict__ wq2,
    const float* __restrict__ wps, const float* __restrict__ wpc,
    u16* __restrict__ ws16)
{
    const int z = blockIdx.z;
    const int tid = threadIdx.x;
    if (z >= 64) {
        const int widx = z - 64;
        const float* w = widx == 0 ? wq1 : widx == 1 ? wk : widx == 2 ? wv
                       : widx == 3 ? wq2 : widx == 4 ? wps : wpc;
        const int linear = blockIdx.x + 16 * blockIdx.y;   // 0..63
        const int e = linear * 1024 + tid * 4;
        float4 v = *(const float4*)&w[e];
        ushort4 o = make_ushort4(f2b(v.x), f2b(v.y), f2b(v.z), f2b(v.w));
        *(ushort4*)&ws16[WBo + (size_t)widx * 65536 + e] = o;
        return;
    }
    const int which = z >> 5, b = z & 31;
    const float* x = which ? x2 : x1;
    u16* xt = ws16 + (which ? XT2o : XT1o);
    const int p0 = blockIdx.x * 64, c0 = blockIdx.y * 64;
    __shared__ __align__(16) u16 T[64][80];
    #pragma unroll
    for (int i = 0; i < 4; i++) {
        int e = tid + i * 256;
        int c = e >> 4, p4 = e & 15;
        float4 v = *(const float4*)&x[((size_t)(b * Cn + c0 + c)) * Pn + p0 + p4 * 4];
        T[p4 * 4 + 0][c] = f2b(v.x);
        T[p4 * 4 + 1][c] = f2b(v.y);
        T[p4 * 4 + 2][c] = f2b(v.z);
        T[p4 * 4 + 3][c] = f2b(v.w);
    }
    __syncthreads();
    #pragma unroll
    for (int i = 0; i < 2; i++) {
        int e = tid + i * 256;
        int p = e >> 3, c8 = e & 7;
        u16x8 vv = *(const u16x8*)&T[p][c8 * 8];
        *(u16x8*)&xt[((size_t)(b * Pn + p0 + p)) * Cn + c0 + c8 * 8] = vv;
    }
}

// ---------------------------------------------------------------------------
// Shared 128x128x256 MFMA GEMM core: C[m][n] = sum_k A[m][k]*B[n][k], bf16.
// A rows at Ab (stride 256 u16), B rows at Bb. 256 threads = 4 waves (2x2).
// Result in acc[16] (wave-local 4x4 grid of 16x16 tiles).
// ---------------------------------------------------------------------------
__device__ __forceinline__ void gemm_core(
    const u16* __restrict__ Ab, const u16* __restrict__ Bb,
    u16* __restrict__ As, u16* __restrict__ Bs, f32x4 acc[16], int tid)
{
    const int wv = tid >> 6, lane = tid & 63;
    const int ln = lane & 15, quad = lane >> 4;
    const int wr = wv >> 1, wc = wv & 1;
    for (int k0 = 0; k0 < 256; k0 += 64) {
        __syncthreads();
        #pragma unroll
        for (int i = 0; i < 4; i++) {
            int e = tid + i * 256;
            int row = e >> 3, ch = e & 7;
            int pos = ch ^ (row & 7);
            *(u16x8*)&As[row * 64 + pos * 8] =
                *(const u16x8*)&Ab[(size_t)row * 256 + k0 + ch * 8];
            *(u16x8*)&Bs[row * 64 + pos * 8] =
                *(const u16x8*)&Bb[(size_t)row * 256 + k0 + ch * 8];
        }
        __syncthreads();
        bf16x8 af[4][2], bf[4][2];
        #pragma unroll
        for (int i = 0; i < 4; i++) {
            int row = wr * 64 + i * 16 + ln;
            #pragma unroll
            for (int kc = 0; kc < 2; kc++) {
                int pos = (kc * 4 + quad) ^ (row & 7);
                af[i][kc] = *(const bf16x8*)&As[row * 64 + pos * 8];
            }
        }
        #pragma unroll
        for (int j = 0; j < 4; j++) {
            int row = wc * 64 + j * 16 + ln;
            #pragma unroll
            for (int kc = 0; kc < 2; kc++) {
                int pos = (kc * 4 + quad) ^ (row & 7);
                bf[j][kc] = *(const bf16x8*)&Bs[row * 64 + pos * 8];
            }
        }
        #pragma unroll
        for (int kc = 0; kc < 2; kc++)
            #pragma unroll
            for (int i = 0; i < 4; i++)
                #pragma unroll
                for (int j = 0; j < 4; j++)
                    acc[i * 4 + j] = __builtin_amdgcn_mfma_f32_16x16x32_bf16(
                        af[i][kc], bf[j][kc], acc[i * 4 + j], 0, 0, 0);
    }
}

// ---------------------------------------------------------------------------
// proj: q1/k/q2 (mat y=0,1,2): [32768 x 256] = xt . W^T ; V (y=3): vt = W . xt^T
// grid (512, 4); block 256
// ---------------------------------------------------------------------------
__global__ __launch_bounds__(256) void proj_kernel(
    u16* __restrict__ ws16,
    const float* __restrict__ bq1, const float* __restrict__ bk,
    const float* __restrict__ bq2, const float* __restrict__ bv)
{
    __shared__ __align__(16) u16 As[128 * 64];
    __shared__ __align__(16) u16 Bs[128 * 64];
    const int tid = threadIdx.x;
    const int mat = blockIdx.y;
    const int wv = tid >> 6, lane = tid & 63;
    const int ln = lane & 15, quad = lane >> 4;
    const int wr = wv >> 1, wc = wv & 1;

    f32x4 acc[16];
    #pragma unroll
    for (int t = 0; t < 16; t++) acc[t] = (f32x4){0.f, 0.f, 0.f, 0.f};

    if (mat < 3) {
        // mat: 0=q1(x1,wq1,s), 1=k(x1,wk), 2=q2(x2,wq2,s)
        const int m_tile = blockIdx.x >> 1, n_tile = blockIdx.x & 1;
        const size_t xtoff = (mat == 2) ? XT2o : XT1o;
        const int widx = (mat == 0) ? 0 : (mat == 1) ? 1 : 3;
        const float* bias = (mat == 0) ? bq1 : (mat == 1) ? bk : bq2;
        const float scale = (mat == 1) ? 1.0f : 0.0625f;
        u16* out = ws16 + ((mat == 0) ? Q1o : (mat == 1) ? Ko : Q2o);

        const u16* Ab = ws16 + xtoff + (size_t)m_tile * 128 * 256;
        const u16* Bb = ws16 + WBo + (size_t)widx * 65536 + (size_t)n_tile * 128 * 256;
        gemm_core(Ab, Bb, As, Bs, acc, tid);

        const int m0 = m_tile * 128;
        #pragma unroll
        for (int j = 0; j < 4; j++) {
            const int ncol = n_tile * 128 + wc * 64 + j * 16 + ln;
            const float bj = bias[ncol];
            #pragma unroll
            for (int i = 0; i < 4; i++) {
                const int mr = m0 + wr * 64 + i * 16 + quad * 4;
                #pragma unroll
                for (int r = 0; r < 4; r++)
                    out[(size_t)(mr + r) * 256 + ncol] =
                        f2b((acc[i * 4 + j][r] + bj) * scale);
            }
        }
    } else {
        // V: per-batch vt[b][o][p] = sum_c wv[o][c] * xt1[b*1024+p][c] + bv[o]
        const int b = blockIdx.x >> 4;
        const int o_tile = (blockIdx.x >> 3) & 1;
        const int p_tile = blockIdx.x & 7;
        const u16* Ab = ws16 + WBo + (size_t)2 * 65536 + (size_t)o_tile * 128 * 256;
        const u16* Bb = ws16 + XT1o + ((size_t)b * Pn + p_tile * 128) * 256;
        gemm_core(Ab, Bb, As, Bs, acc, tid);

        u16* vt = ws16 + VTo + (size_t)b * Cn * Pn;
        #pragma unroll
        for (int i = 0; i < 4; i++) {
            #pragma unroll
            for (int r = 0; r < 4; r++) {
                const int orow = o_tile * 128 + wr * 64 + i * 16 + quad * 4 + r;
                const float bo = bv[orow];
                #pragma unroll
                for (int j = 0; j < 4; j++) {
                    const int pcol = p_tile * 128 + wc * 64 + j * 16 + ln;
                    vt[(size_t)orow * Pn + pcol] = f2b(acc[i * 4 + j][r] + bo);
                }
            }
        }
    }
}

// ---------------------------------------------------------------------------
// attn: bf16-MFMA flash attention, dual-path (unchanged core from R2).
// grid (Pn/32, Bn); block 256
// ---------------------------------------------------------------------------
__global__ __launch_bounds__(256) void attn_kernel(u16* __restrict__ ws16)
{
    const u16* Q1 = ws16 + Q1o;
    const u16* Kg = ws16 + Ko;
    const u16* Vt = ws16 + VTo;
    const u16* Q2 = ws16 + Q2o;

    __shared__ __align__(16) u16  Klds[32 * 256];
    __shared__ __align__(16) u16  Vtlds[256 * 32];
    __shared__ float S1lds[32 * 33];
    __shared__ __align__(16) u16  Plds[2 * 32 * 40];

    const int b    = blockIdx.y;
    const int q0   = blockIdx.x * 32;
    const int tid  = threadIdx.x;
    const int wv   = tid >> 6;
    const int path = wv >> 1;
    const int qsub = wv & 1;
    const int lane = tid & 63;
    const int ln   = lane & 15;
    const int quad = lane >> 4;
    const int pbase = path * (32 * 40);

    const u16* Qg = path ? Q2 : Q1;
    const size_t qrow = (size_t)(b * Pn + q0 + qsub * 16 + ln) * Cn;
    bf16x8 qa[8];
    #pragma unroll
    for (int ch = 0; ch < 8; ch++)
        qa[ch] = *(const bf16x8*)&Qg[qrow + ch * 32 + quad * 8];

    f32x4 acc[16];
    #pragma unroll
    for (int t = 0; t < 16; t++) acc[t] = (f32x4){0.f, 0.f, 0.f, 0.f};
    float mrow[4] = {-1e30f, -1e30f, -1e30f, -1e30f};
    float lrow[4] = {0.f, 0.f, 0.f, 0.f};

    for (int kt = 0; kt < 32; kt++) {
        const int k0 = kt * 32;
        __syncthreads();

        {
            const int tok = tid >> 3, gi = tid & 7;
            const size_t grow = (size_t)(b * Pn + k0 + tok) * Cn;
            #pragma unroll
            for (int i = 0; i < 4; i++) {
                int glog = 8 * i + (gi ^ (tok & 7));
                *(u16x8*)&Klds[tok * 256 + (8 * i + gi) * 8] =
                    *(const u16x8*)&Kg[grow + glog * 8];
            }
        }
        {
            const int cb = tid >> 2, g = tid & 3;
            #pragma unroll
            for (int i = 0; i < 4; i++) {
                int cl = cb + 64 * i;
                int gp = g ^ (cl & 3);
                *(u16x8*)&Vtlds[cl * 32 + gp * 8] =
                    *(const u16x8*)&Vt[((size_t)(b * Cn + cl)) * Pn + k0 + g * 8];
            }
        }
        __syncthreads();

        float sv[2][4];
        #pragma unroll
        for (int st = 0; st < 2; st++) {
            f32x4 s = (f32x4){0.f, 0.f, 0.f, 0.f};
            #pragma unroll
            for (int ch = 0; ch < 8; ch++) {
                bf16x8 kb = *(const bf16x8*)
                    &Klds[(st * 16 + ln) * 256 + (((ch * 4 + quad) ^ (ln & 7))) * 8];
                s = __builtin_amdgcn_mfma_f32_16x16x32_bf16(qa[ch], kb, s, 0, 0, 0);
            }
            #pragma unroll
            for (int r = 0; r < 4; r++) sv[st][r] = s[r];
        }
        if (path == 0) {
            #pragma unroll
            for (int st = 0; st < 2; st++)
                #pragma unroll
                for (int r = 0; r < 4; r++)
                    S1lds[(qsub * 16 + quad * 4 + r) * 33 + st * 16 + ln] = sv[st][r];
        }
        __syncthreads();
        if (path == 1) {
            #pragma unroll
            for (int st = 0; st < 2; st++)
                #pragma unroll
                for (int r = 0; r < 4; r++)
                    sv[st][r] += S1lds[(qsub * 16 + quad * 4 + r) * 33 + st * 16 + ln];
        }

        #pragma unroll
        for (int r = 0; r < 4; r++) {
            float mx = fmaxf(sv[0][r], sv[1][r]);
            mx = fmaxf(mx, __shfl_xor(mx, 1));
            mx = fmaxf(mx, __shfl_xor(mx, 2));
            mx = fmaxf(mx, __shfl_xor(mx, 4));
            mx = fmaxf(mx, __shfl_xor(mx, 8));
            float mn = fmaxf(mrow[r], mx);
            float al = __expf(mrow[r] - mn);
            float p0 = __expf(sv[0][r] - mn);
            float p1 = __expf(sv[1][r] - mn);
            float rs = p0 + p1;
            rs += __shfl_xor(rs, 1);
            rs += __shfl_xor(rs, 2);
            rs += __shfl_xor(rs, 4);
            rs += __shfl_xor(rs, 8);
            lrow[r] = lrow[r] * al + rs;
            mrow[r] = mn;
            #pragma unroll
            for (int t = 0; t < 16; t++) acc[t][r] *= al;
            int q_l = qsub * 16 + quad * 4 + r;
            Plds[pbase + q_l * 40 + ln]      = f2b(p0);
            Plds[pbase + q_l * 40 + 16 + ln] = f2b(p1);
        }

        bf16x8 pa = *(const bf16x8*)&Plds[pbase + (qsub * 16 + ln) * 40 + quad * 8];
        #pragma unroll
        for (int t = 0; t < 16; t++) {
            bf16x8 vb = *(const bf16x8*)
                &Vtlds[(t * 16 + ln) * 32 + (quad ^ (ln & 3)) * 8];
            acc[t] = __builtin_amdgcn_mfma_f32_16x16x32_bf16(pa, vb, acc[t], 0, 0, 0);
        }
    }

    u16* H = ws16 + (path ? H12o : H1o);
    #pragma unroll
    for (int r = 0; r < 4; r++) {
        float inv = 1.f / lrow[r];
        size_t rowb = (size_t)(b * Pn + q0 + qsub * 16 + quad * 4 + r) * Cn;
        #pragma unroll
        for (int t = 0; t < 16; t++)
            H[rowb + t * 16 + ln] = f2b(acc[t][r] * inv);
    }
}

// ---------------------------------------------------------------------------
// outproj: out[mat][b][o][p] = x1[b][o][p] + bias[o] + sum_c h[b][p][c]*w[o][c]
// grid (16, 64); block 256
// ---------------------------------------------------------------------------
__global__ __launch_bounds__(256) void outproj_kernel(
    const float* __restrict__ x1,
    const float* __restrict__ bps, const float* __restrict__ bpc,
    const u16* __restrict__ ws16, float* __restrict__ outp)
{
    __shared__ __align__(16) u16 As[128 * 64];
    __shared__ __align__(16) u16 Bs[128 * 64];
    const int tid = threadIdx.x;
    const int o_tile = blockIdx.x >> 3, p_tile = blockIdx.x & 7;
    const int mat = blockIdx.y >> 5, b = blockIdx.y & 31;
    const int wv = tid >> 6, lane = tid & 63;
    const int ln = lane & 15, quad = lane >> 4;
    const int wr = wv >> 1, wc = wv & 1;

    f32x4 acc[16];
    #pragma unroll
    for (int t = 0; t < 16; t++) acc[t] = (f32x4){0.f, 0.f, 0.f, 0.f};

    const u16* Ab = ws16 + WBo + (size_t)(4 + mat) * 65536 + (size_t)o_tile * 128 * 256;
    const u16* Bb = ws16 + (mat ? H12o : H1o) + ((size_t)b * Pn + p_tile * 128) * 256;
    gemm_core(Ab, Bb, As, Bs, acc, tid);

    const float* bias = mat ? bpc : bps;
    float* out = outp + (size_t)mat * Tn;
    #pragma unroll
    for (int i = 0; i < 4; i++) {
        #pragma unroll
        for (int r = 0; r < 4; r++) {
            const int orow = o_tile * 128 + wr * 64 + i * 16 + quad * 4 + r;
            const float bo = bias[orow];
            #pragma unroll
            for (int j = 0; j < 4; j++) {
                const int pcol = p_tile * 128 + wc * 64 + j * 16 + ln;
                const size_t idx = ((size_t)b * Cn + orow) * Pn + pcol;
                out[idx] = x1[idx] + bo + acc[i * 4 + j][r];
            }
        }
    }
}

// ---------------------------------------------------------------------------
extern "C" void kernel_launch(void* const* d_in, const int* in_sizes, int n_in,
                              void* d_out, int out_size, void* d_ws, size_t ws_size,
                              hipStream_t stream)
{
    const float* x1  = (const float*)d_in[0];
    const float* x2  = (const float*)d_in[1];
    const float* wq1 = (const float*)d_in[2];
    const float* bq1 = (const float*)d_in[3];
    const float* wk  = (const float*)d_in[4];
    const float* bk  = (const float*)d_in[5];
    const float* wv  = (const float*)d_in[6];
    const float* bv  = (const float*)d_in[7];
    const float* wq2 = (const float*)d_in[8];
    const float* bq2 = (const float*)d_in[9];
    const float* wps = (const float*)d_in[10];
    const float* bps = (const float*)d_in[11];
    const float* wpc = (const float*)d_in[12];
    const float* bpc = (const float*)d_in[13];
    float* out = (float*)d_out;
    u16* ws16 = (u16*)d_ws;

    cvt_kernel<<<dim3(16, 4, 70), 256, 0, stream>>>(
        x1, x2, wq1, wk, wv, wq2, wps, wpc, ws16);
    proj_kernel<<<dim3(512, 4), 256, 0, stream>>>(ws16, bq1, bk, bq2, bv);
    attn_kernel<<<dim3(Pn / 32, Bn), 256, 0, stream>>>(ws16);
    outproj_kernel<<<dim3(16, 64), 256, 0, stream>>>(x1, bps, bpc, ws16, out);
}

// Round 4
// 399.879 us; speedup vs baseline: 7.9558x; 1.0088x over previous
//
#include <hip/hip_runtime.h>
#include <math.h>

#define Bn 32
#define Cn 256
#define Pn 1024                       // H*W tokens per batch
#define Tn (Bn * Pn * Cn)             // 8,388,608 elems per [b,p,c] tensor

typedef __bf16 bf16x8 __attribute__((ext_vector_type(8)));
typedef float  f32x4  __attribute__((ext_vector_type(4)));
typedef unsigned short u16;
typedef u16 u16x8 __attribute__((ext_vector_type(8)));

// ws layout in u16 units (total ~129 MiB):
#define XT1o ((size_t)0)              // xt of x1: [b][p][c] bf16
#define XT2o ((size_t)1 * Tn)         // xt of x2
#define Q1o  ((size_t)2 * Tn)         // q1 bf16 [b][p][c], pre-scaled 1/16
#define Ko   ((size_t)3 * Tn)         // k  bf16 [b][p][c]
#define VTo  ((size_t)4 * Tn)         // vt bf16 [b][c][p]
#define Q2o  ((size_t)5 * Tn)         // q2 bf16 [b][p][c], pre-scaled 1/16
#define H1o  ((size_t)6 * Tn)         // h1 bf16 [b][p][c]
#define H12o ((size_t)7 * Tn)         // h12 bf16 [b][p][c]
#define WBo  ((size_t)8 * Tn)         // 6 weight mats bf16 [o][c]: q1,k,v,q2,ps,pc

__device__ __forceinline__ u16 f2b(float f) {
    union { float f; unsigned u; } c; c.f = f;
    return (u16)((c.u + 0x7FFFu + ((c.u >> 16) & 1u)) >> 16);
}

// ---------------------------------------------------------------------------
// cvt: x1,x2 [b][c][p] fp32 -> xt [b][p][c] bf16 ; weights fp32 -> bf16.
// grid (16, 4, 70); block 256.
// ---------------------------------------------------------------------------
__global__ __launch_bounds__(256) void cvt_kernel(
    const float* __restrict__ x1, const float* __restrict__ x2,
    const float* __restrict__ wq1, const float* __restrict__ wk,
    const float* __restrict__ wv,  const float* __restrict__ wq2,
    const float* __restrict__ wps, const float* __restrict__ wpc,
    u16* __restrict__ ws16)
{
    const int z = blockIdx.z;
    const int tid = threadIdx.x;
    if (z >= 64) {
        const int widx = z - 64;
        const float* w = widx == 0 ? wq1 : widx == 1 ? wk : widx == 2 ? wv
                       : widx == 3 ? wq2 : widx == 4 ? wps : wpc;
        const int linear = blockIdx.x + 16 * blockIdx.y;   // 0..63
        const int e = linear * 1024 + tid * 4;
        float4 v = *(const float4*)&w[e];
        ushort4 o = make_ushort4(f2b(v.x), f2b(v.y), f2b(v.z), f2b(v.w));
        *(ushort4*)&ws16[WBo + (size_t)widx * 65536 + e] = o;
        return;
    }
    const int which = z >> 5, b = z & 31;
    const float* x = which ? x2 : x1;
    u16* xt = ws16 + (which ? XT2o : XT1o);
    const int p0 = blockIdx.x * 64, c0 = blockIdx.y * 64;
    __shared__ __align__(16) u16 T[64][80];
    #pragma unroll
    for (int i = 0; i < 4; i++) {
        int e = tid + i * 256;
        int c = e >> 4, p4 = e & 15;
        float4 v = *(const float4*)&x[((size_t)(b * Cn + c0 + c)) * Pn + p0 + p4 * 4];
        T[p4 * 4 + 0][c] = f2b(v.x);
        T[p4 * 4 + 1][c] = f2b(v.y);
        T[p4 * 4 + 2][c] = f2b(v.z);
        T[p4 * 4 + 3][c] = f2b(v.w);
    }
    __syncthreads();
    #pragma unroll
    for (int i = 0; i < 2; i++) {
        int e = tid + i * 256;
        int p = e >> 3, c8 = e & 7;
        u16x8 vv = *(const u16x8*)&T[p][c8 * 8];
        *(u16x8*)&xt[((size_t)(b * Pn + p0 + p)) * Cn + c0 + c8 * 8] = vv;
    }
}

// ---------------------------------------------------------------------------
// Shared 128x128x256 MFMA GEMM core (R3-verified).
// ---------------------------------------------------------------------------
__device__ __forceinline__ void gemm_core(
    const u16* __restrict__ Ab, const u16* __restrict__ Bb,
    u16* __restrict__ As, u16* __restrict__ Bs, f32x4 acc[16], int tid)
{
    const int wv = tid >> 6, lane = tid & 63;
    const int ln = lane & 15, quad = lane >> 4;
    const int wr = wv >> 1, wc = wv & 1;
    for (int k0 = 0; k0 < 256; k0 += 64) {
        __syncthreads();
        #pragma unroll
        for (int i = 0; i < 4; i++) {
            int e = tid + i * 256;
            int row = e >> 3, ch = e & 7;
            int pos = ch ^ (row & 7);
            *(u16x8*)&As[row * 64 + pos * 8] =
                *(const u16x8*)&Ab[(size_t)row * 256 + k0 + ch * 8];
            *(u16x8*)&Bs[row * 64 + pos * 8] =
                *(const u16x8*)&Bb[(size_t)row * 256 + k0 + ch * 8];
        }
        __syncthreads();
        bf16x8 af[4][2], bf[4][2];
        #pragma unroll
        for (int i = 0; i < 4; i++) {
            int row = wr * 64 + i * 16 + ln;
            #pragma unroll
            for (int kc = 0; kc < 2; kc++) {
                int pos = (kc * 4 + quad) ^ (row & 7);
                af[i][kc] = *(const bf16x8*)&As[row * 64 + pos * 8];
            }
        }
        #pragma unroll
        for (int j = 0; j < 4; j++) {
            int row = wc * 64 + j * 16 + ln;
            #pragma unroll
            for (int kc = 0; kc < 2; kc++) {
                int pos = (kc * 4 + quad) ^ (row & 7);
                bf[j][kc] = *(const bf16x8*)&Bs[row * 64 + pos * 8];
            }
        }
        #pragma unroll
        for (int kc = 0; kc < 2; kc++)
            #pragma unroll
            for (int i = 0; i < 4; i++)
                #pragma unroll
                for (int j = 0; j < 4; j++)
                    acc[i * 4 + j] = __builtin_amdgcn_mfma_f32_16x16x32_bf16(
                        af[i][kc], bf[j][kc], acc[i * 4 + j], 0, 0, 0);
    }
}

// ---------------------------------------------------------------------------
// proj: q1/k/q2 (mat 0,1,2): [32768 x 256] = xt . W^T ; V (mat 3): vt = W . xt^T
// grid (512, 4); block 256
// ---------------------------------------------------------------------------
__global__ __launch_bounds__(256) void proj_kernel(
    u16* __restrict__ ws16,
    const float* __restrict__ bq1, const float* __restrict__ bk,
    const float* __restrict__ bq2, const float* __restrict__ bv)
{
    __shared__ __align__(16) u16 As[128 * 64];
    __shared__ __align__(16) u16 Bs[128 * 64];
    const int tid = threadIdx.x;
    const int mat = blockIdx.y;
    const int wv = tid >> 6, lane = tid & 63;
    const int ln = lane & 15, quad = lane >> 4;
    const int wr = wv >> 1, wc = wv & 1;

    f32x4 acc[16];
    #pragma unroll
    for (int t = 0; t < 16; t++) acc[t] = (f32x4){0.f, 0.f, 0.f, 0.f};

    if (mat < 3) {
        const int m_tile = blockIdx.x >> 1, n_tile = blockIdx.x & 1;
        const size_t xtoff = (mat == 2) ? XT2o : XT1o;
        const int widx = (mat == 0) ? 0 : (mat == 1) ? 1 : 3;
        const float* bias = (mat == 0) ? bq1 : (mat == 1) ? bk : bq2;
        const float scale = (mat == 1) ? 1.0f : 0.0625f;
        u16* out = ws16 + ((mat == 0) ? Q1o : (mat == 1) ? Ko : Q2o);

        const u16* Ab = ws16 + xtoff + (size_t)m_tile * 128 * 256;
        const u16* Bb = ws16 + WBo + (size_t)widx * 65536 + (size_t)n_tile * 128 * 256;
        gemm_core(Ab, Bb, As, Bs, acc, tid);

        const int m0 = m_tile * 128;
        #pragma unroll
        for (int j = 0; j < 4; j++) {
            const int ncol = n_tile * 128 + wc * 64 + j * 16 + ln;
            const float bj = bias[ncol];
            #pragma unroll
            for (int i = 0; i < 4; i++) {
                const int mr = m0 + wr * 64 + i * 16 + quad * 4;
                #pragma unroll
                for (int r = 0; r < 4; r++)
                    out[(size_t)(mr + r) * 256 + ncol] =
                        f2b((acc[i * 4 + j][r] + bj) * scale);
            }
        }
    } else {
        const int b = blockIdx.x >> 4;
        const int o_tile = (blockIdx.x >> 3) & 1;
        const int p_tile = blockIdx.x & 7;
        const u16* Ab = ws16 + WBo + (size_t)2 * 65536 + (size_t)o_tile * 128 * 256;
        const u16* Bb = ws16 + XT1o + ((size_t)b * Pn + p_tile * 128) * 256;
        gemm_core(Ab, Bb, As, Bs, acc, tid);

        u16* vt = ws16 + VTo + (size_t)b * Cn * Pn;
        #pragma unroll
        for (int i = 0; i < 4; i++) {
            #pragma unroll
            for (int r = 0; r < 4; r++) {
                const int orow = o_tile * 128 + wr * 64 + i * 16 + quad * 4 + r;
                const float bo = bv[orow];
                #pragma unroll
                for (int j = 0; j < 4; j++) {
                    const int pcol = p_tile * 128 + wc * 64 + j * 16 + ln;
                    vt[(size_t)orow * Pn + pcol] = f2b(acc[i * 4 + j][r] + bo);
                }
            }
        }
    }
}

// ---------------------------------------------------------------------------
// attn v2: bf16-MFMA, no-max softmax (inputs bounded), 32 q-rows per wave.
// block = 4 waves: wave = (path, qh); 64 q-rows per block, 32 k per iter.
// grid (Pn/64, Bn) = (16, 32)
// ---------------------------------------------------------------------------
__global__ __launch_bounds__(256, 2) void attn_kernel(u16* __restrict__ ws16)
{
    const u16* Q1 = ws16 + Q1o;
    const u16* Kg = ws16 + Ko;
    const u16* Vt = ws16 + VTo;
    const u16* Q2 = ws16 + Q2o;

    __shared__ __align__(16) u16  Klds[32 * 256];   // [tok][c], gran swizzle ^ (tok&7)
    __shared__ __align__(16) u16  Vtlds[256 * 32];  // [c][tok], gran swizzle ^ (c&3)
    __shared__ float S1lds[64 * 33];                // fp32 S1 exchange, 64 q rows
    __shared__ __align__(16) u16  Plds[2 * 64 * 40];// bf16 P per path, row pad 40

    const int b    = blockIdx.y;
    const int q0   = blockIdx.x * 64;
    const int tid  = threadIdx.x;
    const int wv   = tid >> 6;
    const int path = wv >> 1;       // 0 -> H1 (S1), 1 -> H12 (S1+S2)
    const int qh   = wv & 1;        // which 32-row half of the block's 64 rows
    const int lane = tid & 63;
    const int ln   = lane & 15;
    const int quad = lane >> 4;
    const int pbase = path * (64 * 40);

    // resident A-fragments: 32 q rows (2 groups of 16), whole C=256
    const u16* Qg = path ? Q2 : Q1;
    bf16x8 qa[2][8];
    #pragma unroll
    for (int g = 0; g < 2; g++) {
        const size_t qrow = (size_t)(b * Pn + q0 + qh * 32 + g * 16 + ln) * Cn;
        #pragma unroll
        for (int ch = 0; ch < 8; ch++)
            qa[g][ch] = *(const bf16x8*)&Qg[qrow + ch * 32 + quad * 8];
    }

    f32x4 acc[2][16];
    #pragma unroll
    for (int g = 0; g < 2; g++)
        #pragma unroll
        for (int t = 0; t < 16; t++) acc[g][t] = (f32x4){0.f, 0.f, 0.f, 0.f};
    float lp[2][4] = {};

    for (int kt = 0; kt < 32; kt++) {
        const int k0 = kt * 32;
        __syncthreads();   // (A) previous iter's LDS reads all complete

        // stage K tile [32][256]
        {
            const int tok = tid >> 3, gi = tid & 7;
            const size_t grow = (size_t)(b * Pn + k0 + tok) * Cn;
            #pragma unroll
            for (int i = 0; i < 4; i++) {
                int glog = 8 * i + (gi ^ (tok & 7));
                *(u16x8*)&Klds[tok * 256 + (8 * i + gi) * 8] =
                    *(const u16x8*)&Kg[grow + glog * 8];
            }
        }
        // stage Vt tile [256][32]
        {
            const int cb = tid >> 2, gv = tid & 3;
            #pragma unroll
            for (int i = 0; i < 4; i++) {
                int cl = cb + 64 * i;
                int gp = gv ^ (cl & 3);
                *(u16x8*)&Vtlds[cl * 32 + gp * 8] =
                    *(const u16x8*)&Vt[((size_t)(b * Cn + cl)) * Pn + k0 + gv * 8];
            }
        }
        __syncthreads();   // (B) tiles visible

        // scores: both 16-row groups share each kb fragment
        float sv[2][2][4];   // [g][st][r]
        #pragma unroll
        for (int st = 0; st < 2; st++) {
            f32x4 s0 = (f32x4){0.f, 0.f, 0.f, 0.f};
            f32x4 s1 = (f32x4){0.f, 0.f, 0.f, 0.f};
            #pragma unroll
            for (int ch = 0; ch < 8; ch++) {
                bf16x8 kb = *(const bf16x8*)
                    &Klds[(st * 16 + ln) * 256 + (((ch * 4 + quad) ^ (ln & 7))) * 8];
                s0 = __builtin_amdgcn_mfma_f32_16x16x32_bf16(qa[0][ch], kb, s0, 0, 0, 0);
                s1 = __builtin_amdgcn_mfma_f32_16x16x32_bf16(qa[1][ch], kb, s1, 0, 0, 0);
            }
            #pragma unroll
            for (int r = 0; r < 4; r++) { sv[0][st][r] = s0[r]; sv[1][st][r] = s1[r]; }
        }

        if (path == 0) {
            // publish S1, then exp (no max subtraction: scores bounded)
            #pragma unroll
            for (int g = 0; g < 2; g++)
                #pragma unroll
                for (int st = 0; st < 2; st++)
                    #pragma unroll
                    for (int r = 0; r < 4; r++)
                        S1lds[(qh * 32 + g * 16 + quad * 4 + r) * 33 + st * 16 + ln]
                            = sv[g][st][r];
            #pragma unroll
            for (int g = 0; g < 2; g++)
                #pragma unroll
                for (int r = 0; r < 4; r++) {
                    float p0 = __expf(sv[g][0][r]);
                    float p1 = __expf(sv[g][1][r]);
                    lp[g][r] += p0 + p1;
                    int row = qh * 32 + g * 16 + quad * 4 + r;
                    Plds[pbase + row * 40 + ln]      = f2b(p0);
                    Plds[pbase + row * 40 + 16 + ln] = f2b(p1);
                }
        }
        __syncthreads();   // (C) S1 visible to path 1
        if (path == 1) {
            #pragma unroll
            for (int g = 0; g < 2; g++)
                #pragma unroll
                for (int r = 0; r < 4; r++) {
                    int row = qh * 32 + g * 16 + quad * 4 + r;
                    float p0 = __expf(sv[g][0][r] + S1lds[row * 33 + ln]);
                    float p1 = __expf(sv[g][1][r] + S1lds[row * 33 + 16 + ln]);
                    lp[g][r] += p0 + p1;
                    Plds[pbase + row * 40 + ln]      = f2b(p0);
                    Plds[pbase + row * 40 + 16 + ln] = f2b(p1);
                }
        }

        // PV: pa per group (same-wave LDS round trip), vb shared by both groups
        bf16x8 pa0 = *(const bf16x8*)&Plds[pbase + (qh * 32 + ln) * 40 + quad * 8];
        bf16x8 pa1 = *(const bf16x8*)&Plds[pbase + (qh * 32 + 16 + ln) * 40 + quad * 8];
        #pragma unroll
        for (int t = 0; t < 16; t++) {
            bf16x8 vb = *(const bf16x8*)
                &Vtlds[(t * 16 + ln) * 32 + (quad ^ (ln & 3)) * 8];
            acc[0][t] = __builtin_amdgcn_mfma_f32_16x16x32_bf16(pa0, vb, acc[0][t], 0, 0, 0);
            acc[1][t] = __builtin_amdgcn_mfma_f32_16x16x32_bf16(pa1, vb, acc[1][t], 0, 0, 0);
        }
    }

    // epilogue: reduce l across the 16 k-lanes once, normalize, store bf16
    u16* H = ws16 + (path ? H12o : H1o);
    #pragma unroll
    for (int g = 0; g < 2; g++)
        #pragma unroll
        for (int r = 0; r < 4; r++) {
            float l = lp[g][r];
            l += __shfl_xor(l, 1);
            l += __shfl_xor(l, 2);
            l += __shfl_xor(l, 4);
            l += __shfl_xor(l, 8);
            float inv = 1.f / l;
            size_t rowb = (size_t)(b * Pn + q0 + qh * 32 + g * 16 + quad * 4 + r) * Cn;
            #pragma unroll
            for (int t = 0; t < 16; t++)
                H[rowb + t * 16 + ln] = f2b(acc[g][t][r] * inv);
        }
}

// ---------------------------------------------------------------------------
// outproj: out[mat][b][o][p] = x1[b][o][p] + bias[o] + sum_c h[b][p][c]*w[o][c]
// grid (16, 64); block 256
// ---------------------------------------------------------------------------
__global__ __launch_bounds__(256) void outproj_kernel(
    const float* __restrict__ x1,
    const float* __restrict__ bps, const float* __restrict__ bpc,
    const u16* __restrict__ ws16, float* __restrict__ outp)
{
    __shared__ __align__(16) u16 As[128 * 64];
    __shared__ __align__(16) u16 Bs[128 * 64];
    const int tid = threadIdx.x;
    const int o_tile = blockIdx.x >> 3, p_tile = blockIdx.x & 7;
    const int mat = blockIdx.y >> 5, b = blockIdx.y & 31;
    const int wv = tid >> 6, lane = tid & 63;
    const int ln = lane & 15, quad = lane >> 4;
    const int wr = wv >> 1, wc = wv & 1;

    f32x4 acc[16];
    #pragma unroll
    for (int t = 0; t < 16; t++) acc[t] = (f32x4){0.f, 0.f, 0.f, 0.f};

    const u16* Ab = ws16 + WBo + (size_t)(4 + mat) * 65536 + (size_t)o_tile * 128 * 256;
    const u16* Bb = ws16 + (mat ? H12o : H1o) + ((size_t)b * Pn + p_tile * 128) * 256;
    gemm_core(Ab, Bb, As, Bs, acc, tid);

    const float* bias = mat ? bpc : bps;
    float* out = outp + (size_t)mat * Tn;
    #pragma unroll
    for (int i = 0; i < 4; i++) {
        #pragma unroll
        for (int r = 0; r < 4; r++) {
            const int orow = o_tile * 128 + wr * 64 + i * 16 + quad * 4 + r;
            const float bo = bias[orow];
            #pragma unroll
            for (int j = 0; j < 4; j++) {
                const int pcol = p_tile * 128 + wc * 64 + j * 16 + ln;
                const size_t idx = ((size_t)b * Cn + orow) * Pn + pcol;
                out[idx] = x1[idx] + bo + acc[i * 4 + j][r];
            }
        }
    }
}

// ---------------------------------------------------------------------------
extern "C" void kernel_launch(void* const* d_in, const int* in_sizes, int n_in,
                              void* d_out, int out_size, void* d_ws, size_t ws_size,
                              hipStream_t stream)
{
    const float* x1  = (const float*)d_in[0];
    const float* x2  = (const float*)d_in[1];
    const float* wq1 = (const float*)d_in[2];
    const float* bq1 = (const float*)d_in[3];
    const float* wk  = (const float*)d_in[4];
    const float* bk  = (const float*)d_in[5];
    const float* wv  = (const float*)d_in[6];
    const float* bv  = (const float*)d_in[7];
    const float* wq2 = (const float*)d_in[8];
    const float* bq2 = (const float*)d_in[9];
    const float* wps = (const float*)d_in[10];
    const float* bps = (const float*)d_in[11];
    const float* wpc = (const float*)d_in[12];
    const float* bpc = (const float*)d_in[13];
    float* out = (float*)d_out;
    u16* ws16 = (u16*)d_ws;

    cvt_kernel<<<dim3(16, 4, 70), 256, 0, stream>>>(
        x1, x2, wq1, wk, wv, wq2, wps, wpc, ws16);
    proj_kernel<<<dim3(512, 4), 256, 0, stream>>>(ws16, bq1, bk, bq2, bv);
    attn_kernel<<<dim3(Pn / 64, Bn), 256, 0, stream>>>(ws16);
    outproj_kernel<<<dim3(16, 64), 256, 0, stream>>>(x1, bps, bpc, ws16, out);
}

// Round 5
// 300.879 us; speedup vs baseline: 10.5735x; 1.3290x over previous
//
#include <hip/hip_runtime.h>
#include <math.h>

#define Bn 32
#define Cn 256
#define Pn 1024                       // H*W tokens per batch
#define Tn (Bn * Pn * Cn)             // 8,388,608 elems per [b,p,c] tensor

typedef __bf16 bf16x8 __attribute__((ext_vector_type(8)));
typedef float  f32x4  __attribute__((ext_vector_type(4)));
typedef unsigned short u16;
typedef u16 u16x8 __attribute__((ext_vector_type(8)));

// ws layout in u16 units (total ~129 MiB):
#define XT1o ((size_t)0)              // xt of x1: [b][p][c] bf16
#define XT2o ((size_t)1 * Tn)         // xt of x2
#define Q1o  ((size_t)2 * Tn)         // q1 bf16 [b][p][c], pre-scaled 1/16
#define Ko   ((size_t)3 * Tn)         // k  bf16 [b][p][c]
#define VTo  ((size_t)4 * Tn)         // vt bf16 [b][c][p]
#define Q2o  ((size_t)5 * Tn)         // q2 bf16 [b][p][c], pre-scaled 1/16
#define H1o  ((size_t)6 * Tn)         // h1 bf16 [b][p][c]
#define H12o ((size_t)7 * Tn)         // h12 bf16 [b][p][c]
#define WBo  ((size_t)8 * Tn)         // 6 weight mats bf16 [o][c]: q1,k,v,q2,ps,pc

__device__ __forceinline__ u16 f2b(float f) {
    union { float f; unsigned u; } c; c.f = f;
    return (u16)((c.u + 0x7FFFu + ((c.u >> 16) & 1u)) >> 16);
}

// ---------------------------------------------------------------------------
// cvt: x1,x2 [b][c][p] fp32 -> xt [b][p][c] bf16 ; weights fp32 -> bf16.
// grid (16, 4, 70); block 256.
// ---------------------------------------------------------------------------
__global__ __launch_bounds__(256) void cvt_kernel(
    const float* __restrict__ x1, const float* __restrict__ x2,
    const float* __restrict__ wq1, const float* __restrict__ wk,
    const float* __restrict__ wv,  const float* __restrict__ wq2,
    const float* __restrict__ wps, const float* __restrict__ wpc,
    u16* __restrict__ ws16)
{
    const int z = blockIdx.z;
    const int tid = threadIdx.x;
    if (z >= 64) {
        const int widx = z - 64;
        const float* w = widx == 0 ? wq1 : widx == 1 ? wk : widx == 2 ? wv
                       : widx == 3 ? wq2 : widx == 4 ? wps : wpc;
        const int linear = blockIdx.x + 16 * blockIdx.y;   // 0..63
        const int e = linear * 1024 + tid * 4;
        float4 v = *(const float4*)&w[e];
        ushort4 o = make_ushort4(f2b(v.x), f2b(v.y), f2b(v.z), f2b(v.w));
        *(ushort4*)&ws16[WBo + (size_t)widx * 65536 + e] = o;
        return;
    }
    const int which = z >> 5, b = z & 31;
    const float* x = which ? x2 : x1;
    u16* xt = ws16 + (which ? XT2o : XT1o);
    const int p0 = blockIdx.x * 64, c0 = blockIdx.y * 64;
    __shared__ __align__(16) u16 T[64][80];
    #pragma unroll
    for (int i = 0; i < 4; i++) {
        int e = tid + i * 256;
        int c = e >> 4, p4 = e & 15;
        float4 v = *(const float4*)&x[((size_t)(b * Cn + c0 + c)) * Pn + p0 + p4 * 4];
        T[p4 * 4 + 0][c] = f2b(v.x);
        T[p4 * 4 + 1][c] = f2b(v.y);
        T[p4 * 4 + 2][c] = f2b(v.z);
        T[p4 * 4 + 3][c] = f2b(v.w);
    }
    __syncthreads();
    #pragma unroll
    for (int i = 0; i < 2; i++) {
        int e = tid + i * 256;
        int p = e >> 3, c8 = e & 7;
        u16x8 vv = *(const u16x8*)&T[p][c8 * 8];
        *(u16x8*)&xt[((size_t)(b * Pn + p0 + p)) * Cn + c0 + c8 * 8] = vv;
    }
}

// ---------------------------------------------------------------------------
// Shared 128x128x256 MFMA GEMM core (R3-verified).
// ---------------------------------------------------------------------------
__device__ __forceinline__ void gemm_core(
    const u16* __restrict__ Ab, const u16* __restrict__ Bb,
    u16* __restrict__ As, u16* __restrict__ Bs, f32x4 acc[16], int tid)
{
    const int wv = tid >> 6, lane = tid & 63;
    const int ln = lane & 15, quad = lane >> 4;
    const int wr = wv >> 1, wc = wv & 1;
    for (int k0 = 0; k0 < 256; k0 += 64) {
        __syncthreads();
        #pragma unroll
        for (int i = 0; i < 4; i++) {
            int e = tid + i * 256;
            int row = e >> 3, ch = e & 7;
            int pos = ch ^ (row & 7);
            *(u16x8*)&As[row * 64 + pos * 8] =
                *(const u16x8*)&Ab[(size_t)row * 256 + k0 + ch * 8];
            *(u16x8*)&Bs[row * 64 + pos * 8] =
                *(const u16x8*)&Bb[(size_t)row * 256 + k0 + ch * 8];
        }
        __syncthreads();
        bf16x8 af[4][2], bf[4][2];
        #pragma unroll
        for (int i = 0; i < 4; i++) {
            int row = wr * 64 + i * 16 + ln;
            #pragma unroll
            for (int kc = 0; kc < 2; kc++) {
                int pos = (kc * 4 + quad) ^ (row & 7);
                af[i][kc] = *(const bf16x8*)&As[row * 64 + pos * 8];
            }
        }
        #pragma unroll
        for (int j = 0; j < 4; j++) {
            int row = wc * 64 + j * 16 + ln;
            #pragma unroll
            for (int kc = 0; kc < 2; kc++) {
                int pos = (kc * 4 + quad) ^ (row & 7);
                bf[j][kc] = *(const bf16x8*)&Bs[row * 64 + pos * 8];
            }
        }
        #pragma unroll
        for (int kc = 0; kc < 2; kc++)
            #pragma unroll
            for (int i = 0; i < 4; i++)
                #pragma unroll
                for (int j = 0; j < 4; j++)
                    acc[i * 4 + j] = __builtin_amdgcn_mfma_f32_16x16x32_bf16(
                        af[i][kc], bf[j][kc], acc[i * 4 + j], 0, 0, 0);
    }
}

// ---------------------------------------------------------------------------
// proj: q1/k/q2 (mat 0,1,2): [32768 x 256] = xt . W^T ; V (mat 3): vt = W . xt^T
// grid (512, 4); block 256
// ---------------------------------------------------------------------------
__global__ __launch_bounds__(256) void proj_kernel(
    u16* __restrict__ ws16,
    const float* __restrict__ bq1, const float* __restrict__ bk,
    const float* __restrict__ bq2, const float* __restrict__ bv)
{
    __shared__ __align__(16) u16 As[128 * 64];
    __shared__ __align__(16) u16 Bs[128 * 64];
    const int tid = threadIdx.x;
    const int mat = blockIdx.y;
    const int wv = tid >> 6, lane = tid & 63;
    const int ln = lane & 15, quad = lane >> 4;
    const int wr = wv >> 1, wc = wv & 1;

    f32x4 acc[16];
    #pragma unroll
    for (int t = 0; t < 16; t++) acc[t] = (f32x4){0.f, 0.f, 0.f, 0.f};

    if (mat < 3) {
        const int m_tile = blockIdx.x >> 1, n_tile = blockIdx.x & 1;
        const size_t xtoff = (mat == 2) ? XT2o : XT1o;
        const int widx = (mat == 0) ? 0 : (mat == 1) ? 1 : 3;
        const float* bias = (mat == 0) ? bq1 : (mat == 1) ? bk : bq2;
        const float scale = (mat == 1) ? 1.0f : 0.0625f;
        u16* out = ws16 + ((mat == 0) ? Q1o : (mat == 1) ? Ko : Q2o);

        const u16* Ab = ws16 + xtoff + (size_t)m_tile * 128 * 256;
        const u16* Bb = ws16 + WBo + (size_t)widx * 65536 + (size_t)n_tile * 128 * 256;
        gemm_core(Ab, Bb, As, Bs, acc, tid);

        const int m0 = m_tile * 128;
        #pragma unroll
        for (int j = 0; j < 4; j++) {
            const int ncol = n_tile * 128 + wc * 64 + j * 16 + ln;
            const float bj = bias[ncol];
            #pragma unroll
            for (int i = 0; i < 4; i++) {
                const int mr = m0 + wr * 64 + i * 16 + quad * 4;
                #pragma unroll
                for (int r = 0; r < 4; r++)
                    out[(size_t)(mr + r) * 256 + ncol] =
                        f2b((acc[i * 4 + j][r] + bj) * scale);
            }
        }
    } else {
        const int b = blockIdx.x >> 4;
        const int o_tile = (blockIdx.x >> 3) & 1;
        const int p_tile = blockIdx.x & 7;
        const u16* Ab = ws16 + WBo + (size_t)2 * 65536 + (size_t)o_tile * 128 * 256;
        const u16* Bb = ws16 + XT1o + ((size_t)b * Pn + p_tile * 128) * 256;
        gemm_core(Ab, Bb, As, Bs, acc, tid);

        u16* vt = ws16 + VTo + (size_t)b * Cn * Pn;
        #pragma unroll
        for (int i = 0; i < 4; i++) {
            #pragma unroll
            for (int r = 0; r < 4; r++) {
                const int orow = o_tile * 128 + wr * 64 + i * 16 + quad * 4 + r;
                const float bo = bv[orow];
                #pragma unroll
                for (int j = 0; j < 4; j++) {
                    const int pcol = p_tile * 128 + wc * 64 + j * 16 + ln;
                    vt[(size_t)orow * Pn + pcol] = f2b(acc[i * 4 + j][r] + bo);
                }
            }
        }
    }
}

// ---------------------------------------------------------------------------
// attn v3: in-wave dual path. Each wave owns 16 q-rows, computes S1 AND S2,
// p12 = exp(s1)*exp(s2). No cross-wave exchange. K/V prefetched into regs.
// block = 4 waves = 64 q-rows; 32 k-tokens per iter. grid (16, 32).
// ---------------------------------------------------------------------------
__global__ __launch_bounds__(256, 2) void attn_kernel(u16* __restrict__ ws16)
{
    const u16* Q1 = ws16 + Q1o;
    const u16* Kg = ws16 + Ko;
    const u16* Vt = ws16 + VTo;
    const u16* Q2 = ws16 + Q2o;

    __shared__ __align__(16) u16 Klds[32 * 256];    // [tok][c], chunk swizzle ^ (tok&7)
    __shared__ __align__(16) u16 Vtlds[256 * 32];   // [c][tok], chunk swizzle ^ (c&3)
    __shared__ __align__(16) u16 Plds[4 * 2 * 16 * 40];  // per-wave P1/P12, pad 40

    const int b    = blockIdx.y;
    const int q0   = blockIdx.x * 64;
    const int tid  = threadIdx.x;
    const int wid  = tid >> 6;
    const int lane = tid & 63;
    const int ln   = lane & 15;
    const int quad = lane >> 4;
    u16* Pw = Plds + wid * (2 * 16 * 40);

    // resident A-fragments: this wave's 16 q rows, both paths, whole C=256
    const size_t qrow = (size_t)(b * Pn + q0 + wid * 16 + ln) * Cn;
    bf16x8 qa1[8], qa2[8];
    #pragma unroll
    for (int ch = 0; ch < 8; ch++) {
        qa1[ch] = *(const bf16x8*)&Q1[qrow + ch * 32 + quad * 8];
        qa2[ch] = *(const bf16x8*)&Q2[qrow + ch * 32 + quad * 8];
    }

    f32x4 acc1[16], acc12[16];
    #pragma unroll
    for (int t = 0; t < 16; t++) {
        acc1[t] = (f32x4){0.f, 0.f, 0.f, 0.f};
        acc12[t] = (f32x4){0.f, 0.f, 0.f, 0.f};
    }
    float lp1[4] = {}, lp12[4] = {};

    // prefetch thread roles (match R4's verified staging layouts)
    const int tokK = tid >> 3, giK = tid & 7;
    const int cbV = tid >> 2, gvV = tid & 3;
    u16x8 kpre[4], vpre[4];

    // prefetch tile 0
    {
        const size_t growK = (size_t)(b * Pn + 0 + tokK) * Cn;
        #pragma unroll
        for (int i = 0; i < 4; i++)
            kpre[i] = *(const u16x8*)&Kg[growK + (size_t)(8 * i + (giK ^ (tokK & 7))) * 8];
        #pragma unroll
        for (int i = 0; i < 4; i++) {
            int cl = cbV + 64 * i;
            vpre[i] = *(const u16x8*)&Vt[((size_t)(b * Cn + cl)) * Pn + 0 + gvV * 8];
        }
    }

    for (int kt = 0; kt < 32; kt++) {
        __syncthreads();   // (A) all waves done reading LDS of prev iter

        // store prefetched tile -> LDS (swizzled positions)
        #pragma unroll
        for (int i = 0; i < 4; i++)
            *(u16x8*)&Klds[tokK * 256 + (8 * i + giK) * 8] = kpre[i];
        #pragma unroll
        for (int i = 0; i < 4; i++) {
            int cl = cbV + 64 * i;
            int gp = gvV ^ (cl & 3);
            *(u16x8*)&Vtlds[cl * 32 + gp * 8] = vpre[i];
        }
        __syncthreads();   // (B) tile visible

        // issue next tile's loads now; they complete during this iter's compute
        if (kt < 31) {
            const int k0n = (kt + 1) * 32;
            const size_t growK = (size_t)(b * Pn + k0n + tokK) * Cn;
            #pragma unroll
            for (int i = 0; i < 4; i++)
                kpre[i] = *(const u16x8*)&Kg[growK + (size_t)(8 * i + (giK ^ (tokK & 7))) * 8];
            #pragma unroll
            for (int i = 0; i < 4; i++) {
                int cl = cbV + 64 * i;
                vpre[i] = *(const u16x8*)&Vt[((size_t)(b * Cn + cl)) * Pn + k0n + gvV * 8];
            }
        }

        // scores: S1 and S2, two 16-wide k subtiles; each kb feeds 2 MFMAs
        float s1v[2][4], s2v[2][4];
        #pragma unroll
        for (int st = 0; st < 2; st++) {
            f32x4 s1 = (f32x4){0.f, 0.f, 0.f, 0.f};
            f32x4 s2 = (f32x4){0.f, 0.f, 0.f, 0.f};
            #pragma unroll
            for (int ch = 0; ch < 8; ch++) {
                bf16x8 kb = *(const bf16x8*)
                    &Klds[(st * 16 + ln) * 256 + (((ch * 4 + quad) ^ (ln & 7))) * 8];
                s1 = __builtin_amdgcn_mfma_f32_16x16x32_bf16(qa1[ch], kb, s1, 0, 0, 0);
                s2 = __builtin_amdgcn_mfma_f32_16x16x32_bf16(qa2[ch], kb, s2, 0, 0, 0);
            }
            #pragma unroll
            for (int r = 0; r < 4; r++) { s1v[st][r] = s1[r]; s2v[st][r] = s2[r]; }
        }

        // exp + P (in-wave, both paths; no max subtraction: logits bounded)
        #pragma unroll
        for (int st = 0; st < 2; st++)
            #pragma unroll
            for (int r = 0; r < 4; r++) {
                float p1 = __expf(s1v[st][r]);
                float p12 = p1 * __expf(s2v[st][r]);
                lp1[r] += p1;
                lp12[r] += p12;
                int row = quad * 4 + r, col = st * 16 + ln;
                Pw[row * 40 + col]            = f2b(p1);
                Pw[16 * 40 + row * 40 + col]  = f2b(p12);
            }

        // PV: pa per path (same-wave LDS round trip), vb shared by both paths
        bf16x8 pa1 = *(const bf16x8*)&Pw[ln * 40 + quad * 8];
        bf16x8 pa2 = *(const bf16x8*)&Pw[16 * 40 + ln * 40 + quad * 8];
        #pragma unroll
        for (int t = 0; t < 16; t++) {
            bf16x8 vb = *(const bf16x8*)
                &Vtlds[(t * 16 + ln) * 32 + (quad ^ (ln & 3)) * 8];
            acc1[t]  = __builtin_amdgcn_mfma_f32_16x16x32_bf16(pa1, vb, acc1[t], 0, 0, 0);
            acc12[t] = __builtin_amdgcn_mfma_f32_16x16x32_bf16(pa2, vb, acc12[t], 0, 0, 0);
        }
    }

    // epilogue: reduce l over the 16 k-lanes, normalize, store bf16
    u16* H1 = ws16 + H1o;
    u16* H12 = ws16 + H12o;
    #pragma unroll
    for (int r = 0; r < 4; r++) {
        float l1 = lp1[r], l2 = lp12[r];
        l1 += __shfl_xor(l1, 1); l2 += __shfl_xor(l2, 1);
        l1 += __shfl_xor(l1, 2); l2 += __shfl_xor(l2, 2);
        l1 += __shfl_xor(l1, 4); l2 += __shfl_xor(l2, 4);
        l1 += __shfl_xor(l1, 8); l2 += __shfl_xor(l2, 8);
        float i1 = 1.f / l1, i2 = 1.f / l2;
        size_t rowb = (size_t)(b * Pn + q0 + wid * 16 + quad * 4 + r) * Cn;
        #pragma unroll
        for (int t = 0; t < 16; t++) {
            H1[rowb + t * 16 + ln]  = f2b(acc1[t][r] * i1);
            H12[rowb + t * 16 + ln] = f2b(acc12[t][r] * i2);
        }
    }
}

// ---------------------------------------------------------------------------
// outproj: out[mat][b][o][p] = x1[b][o][p] + bias[o] + sum_c h[b][p][c]*w[o][c]
// grid (16, 64); block 256
// ---------------------------------------------------------------------------
__global__ __launch_bounds__(256) void outproj_kernel(
    const float* __restrict__ x1,
    const float* __restrict__ bps, const float* __restrict__ bpc,
    const u16* __restrict__ ws16, float* __restrict__ outp)
{
    __shared__ __align__(16) u16 As[128 * 64];
    __shared__ __align__(16) u16 Bs[128 * 64];
    const int tid = threadIdx.x;
    const int o_tile = blockIdx.x >> 3, p_tile = blockIdx.x & 7;
    const int mat = blockIdx.y >> 5, b = blockIdx.y & 31;
    const int wv = tid >> 6, lane = tid & 63;
    const int ln = lane & 15, quad = lane >> 4;
    const int wr = wv >> 1, wc = wv & 1;

    f32x4 acc[16];
    #pragma unroll
    for (int t = 0; t < 16; t++) acc[t] = (f32x4){0.f, 0.f, 0.f, 0.f};

    const u16* Ab = ws16 + WBo + (size_t)(4 + mat) * 65536 + (size_t)o_tile * 128 * 256;
    const u16* Bb = ws16 + (mat ? H12o : H1o) + ((size_t)b * Pn + p_tile * 128) * 256;
    gemm_core(Ab, Bb, As, Bs, acc, tid);

    const float* bias = mat ? bpc : bps;
    float* out = outp + (size_t)mat * Tn;
    #pragma unroll
    for (int i = 0; i < 4; i++) {
        #pragma unroll
        for (int r = 0; r < 4; r++) {
            const int orow = o_tile * 128 + wr * 64 + i * 16 + quad * 4 + r;
            const float bo = bias[orow];
            #pragma unroll
            for (int j = 0; j < 4; j++) {
                const int pcol = p_tile * 128 + wc * 64 + j * 16 + ln;
                const size_t idx = ((size_t)b * Cn + orow) * Pn + pcol;
                out[idx] = x1[idx] + bo + acc[i * 4 + j][r];
            }
        }
    }
}

// ---------------------------------------------------------------------------
extern "C" void kernel_launch(void* const* d_in, const int* in_sizes, int n_in,
                              void* d_out, int out_size, void* d_ws, size_t ws_size,
                              hipStream_t stream)
{
    const float* x1  = (const float*)d_in[0];
    const float* x2  = (const float*)d_in[1];
    const float* wq1 = (const float*)d_in[2];
    const float* bq1 = (const float*)d_in[3];
    const float* wk  = (const float*)d_in[4];
    const float* bk  = (const float*)d_in[5];
    const float* wv  = (const float*)d_in[6];
    const float* bv  = (const float*)d_in[7];
    const float* wq2 = (const float*)d_in[8];
    const float* bq2 = (const float*)d_in[9];
    const float* wps = (const float*)d_in[10];
    const float* bps = (const float*)d_in[11];
    const float* wpc = (const float*)d_in[12];
    const float* bpc = (const float*)d_in[13];
    float* out = (float*)d_out;
    u16* ws16 = (u16*)d_ws;

    cvt_kernel<<<dim3(16, 4, 70), 256, 0, stream>>>(
        x1, x2, wq1, wk, wv, wq2, wps, wpc, ws16);
    proj_kernel<<<dim3(512, 4), 256, 0, stream>>>(ws16, bq1, bk, bq2, bv);
    attn_kernel<<<dim3(Pn / 64, Bn), 256, 0, stream>>>(ws16);
    outproj_kernel<<<dim3(16, 64), 256, 0, stream>>>(x1, bps, bpc, ws16, out);
}

// Round 6
// 294.825 us; speedup vs baseline: 10.7906x; 1.0205x over previous
//
#include <hip/hip_runtime.h>
#include <math.h>

#define Bn 32
#define Cn 256
#define Pn 1024                       // H*W tokens per batch
#define Tn (Bn * Pn * Cn)             // 8,388,608 elems per [b,p,c] tensor

typedef __bf16 bf16x8 __attribute__((ext_vector_type(8)));
typedef float  f32x4  __attribute__((ext_vector_type(4)));
typedef unsigned short u16;
typedef u16 u16x8 __attribute__((ext_vector_type(8)));

// ws layout in u16 units (total ~129 MiB):
#define XT1o ((size_t)0)              // xt of x1: [b][p][c] bf16
#define XT2o ((size_t)1 * Tn)         // xt of x2
#define Q1o  ((size_t)2 * Tn)         // q1 bf16 [b][p][c], pre-scaled 1/16
#define Ko   ((size_t)3 * Tn)         // k  bf16 [b][p][c]
#define VTo  ((size_t)4 * Tn)         // vt bf16 [b][c][p]
#define Q2o  ((size_t)5 * Tn)         // q2 bf16 [b][p][c], pre-scaled 1/16
#define H1o  ((size_t)6 * Tn)         // h1 bf16 [b][p][c]
#define H12o ((size_t)7 * Tn)         // h12 bf16 [b][p][c]
#define WBo  ((size_t)8 * Tn)         // 6 weight mats bf16 [o][c]: q1,k,v,q2,ps,pc

__device__ __forceinline__ u16 f2b(float f) {
    union { float f; unsigned u; } c; c.f = f;
    return (u16)((c.u + 0x7FFFu + ((c.u >> 16) & 1u)) >> 16);
}

// ---------------------------------------------------------------------------
// cvt: x1,x2 [b][c][p] fp32 -> xt [b][p][c] bf16 ; weights fp32 -> bf16.
// grid (16, 4, 70); block 256.
// ---------------------------------------------------------------------------
__global__ __launch_bounds__(256) void cvt_kernel(
    const float* __restrict__ x1, const float* __restrict__ x2,
    const float* __restrict__ wq1, const float* __restrict__ wk,
    const float* __restrict__ wv,  const float* __restrict__ wq2,
    const float* __restrict__ wps, const float* __restrict__ wpc,
    u16* __restrict__ ws16)
{
    const int z = blockIdx.z;
    const int tid = threadIdx.x;
    if (z >= 64) {
        const int widx = z - 64;
        const float* w = widx == 0 ? wq1 : widx == 1 ? wk : widx == 2 ? wv
                       : widx == 3 ? wq2 : widx == 4 ? wps : wpc;
        const int linear = blockIdx.x + 16 * blockIdx.y;   // 0..63
        const int e = linear * 1024 + tid * 4;
        float4 v = *(const float4*)&w[e];
        ushort4 o = make_ushort4(f2b(v.x), f2b(v.y), f2b(v.z), f2b(v.w));
        *(ushort4*)&ws16[WBo + (size_t)widx * 65536 + e] = o;
        return;
    }
    const int which = z >> 5, b = z & 31;
    const float* x = which ? x2 : x1;
    u16* xt = ws16 + (which ? XT2o : XT1o);
    const int p0 = blockIdx.x * 64, c0 = blockIdx.y * 64;
    __shared__ __align__(16) u16 T[64][80];
    #pragma unroll
    for (int i = 0; i < 4; i++) {
        int e = tid + i * 256;
        int c = e >> 4, p4 = e & 15;
        float4 v = *(const float4*)&x[((size_t)(b * Cn + c0 + c)) * Pn + p0 + p4 * 4];
        T[p4 * 4 + 0][c] = f2b(v.x);
        T[p4 * 4 + 1][c] = f2b(v.y);
        T[p4 * 4 + 2][c] = f2b(v.z);
        T[p4 * 4 + 3][c] = f2b(v.w);
    }
    __syncthreads();
    #pragma unroll
    for (int i = 0; i < 2; i++) {
        int e = tid + i * 256;
        int p = e >> 3, c8 = e & 7;
        u16x8 vv = *(const u16x8*)&T[p][c8 * 8];
        *(u16x8*)&xt[((size_t)(b * Pn + p0 + p)) * Cn + c0 + c8 * 8] = vv;
    }
}

// ---------------------------------------------------------------------------
// Shared 128x128x256 MFMA GEMM core, register-prefetch pipeline (R5 lesson):
// chunk k+1's global loads are issued right after chunk k's tiles become
// visible, so VMEM latency hides behind chunk k's frag reads + 32 MFMAs.
// Staging/swizzle layout bit-identical to the R3-verified core.
// ---------------------------------------------------------------------------
__device__ __forceinline__ void gemm_core(
    const u16* __restrict__ Ab, const u16* __restrict__ Bb,
    u16* __restrict__ As, u16* __restrict__ Bs, f32x4 acc[16], int tid)
{
    const int wv = tid >> 6, lane = tid & 63;
    const int ln = lane & 15, quad = lane >> 4;
    const int wr = wv >> 1, wc = wv & 1;
    const int srow = tid >> 3, sch = tid & 7;    // staging role
    const int pos = sch ^ (srow & 7);            // (srow+32i)&7 == srow&7

    u16x8 apre[4], bpre[4];
    #pragma unroll
    for (int i = 0; i < 4; i++) {
        int r = srow + 32 * i;
        apre[i] = *(const u16x8*)&Ab[(size_t)r * 256 + sch * 8];
        bpre[i] = *(const u16x8*)&Bb[(size_t)r * 256 + sch * 8];
    }

    for (int k0 = 0; k0 < 256; k0 += 64) {
        __syncthreads();
        #pragma unroll
        for (int i = 0; i < 4; i++) {
            int r = srow + 32 * i;
            *(u16x8*)&As[r * 64 + pos * 8] = apre[i];
            *(u16x8*)&Bs[r * 64 + pos * 8] = bpre[i];
        }
        __syncthreads();
        if (k0 < 192) {
            #pragma unroll
            for (int i = 0; i < 4; i++) {
                int r = srow + 32 * i;
                apre[i] = *(const u16x8*)&Ab[(size_t)r * 256 + (k0 + 64) + sch * 8];
                bpre[i] = *(const u16x8*)&Bb[(size_t)r * 256 + (k0 + 64) + sch * 8];
            }
        }
        bf16x8 af[4][2], bf[4][2];
        #pragma unroll
        for (int i = 0; i < 4; i++) {
            int row = wr * 64 + i * 16 + ln;
            #pragma unroll
            for (int kc = 0; kc < 2; kc++) {
                int p = (kc * 4 + quad) ^ (row & 7);
                af[i][kc] = *(const bf16x8*)&As[row * 64 + p * 8];
            }
        }
        #pragma unroll
        for (int j = 0; j < 4; j++) {
            int row = wc * 64 + j * 16 + ln;
            #pragma unroll
            for (int kc = 0; kc < 2; kc++) {
                int p = (kc * 4 + quad) ^ (row & 7);
                bf[j][kc] = *(const bf16x8*)&Bs[row * 64 + p * 8];
            }
        }
        #pragma unroll
        for (int kc = 0; kc < 2; kc++)
            #pragma unroll
            for (int i = 0; i < 4; i++)
                #pragma unroll
                for (int j = 0; j < 4; j++)
                    acc[i * 4 + j] = __builtin_amdgcn_mfma_f32_16x16x32_bf16(
                        af[i][kc], bf[j][kc], acc[i * 4 + j], 0, 0, 0);
    }
}

// ---------------------------------------------------------------------------
// proj: q1/k/q2 (mat 0,1,2): [32768 x 256] = xt . W^T ; V (mat 3): vt = W . xt^T
// grid (512, 4); block 256
// ---------------------------------------------------------------------------
__global__ __launch_bounds__(256) void proj_kernel(
    u16* __restrict__ ws16,
    const float* __restrict__ bq1, const float* __restrict__ bk,
    const float* __restrict__ bq2, const float* __restrict__ bv)
{
    __shared__ __align__(16) u16 As[128 * 64];
    __shared__ __align__(16) u16 Bs[128 * 64];
    const int tid = threadIdx.x;
    const int mat = blockIdx.y;
    const int wv = tid >> 6, lane = tid & 63;
    const int ln = lane & 15, quad = lane >> 4;
    const int wr = wv >> 1, wc = wv & 1;

    f32x4 acc[16];
    #pragma unroll
    for (int t = 0; t < 16; t++) acc[t] = (f32x4){0.f, 0.f, 0.f, 0.f};

    if (mat < 3) {
        const int m_tile = blockIdx.x >> 1, n_tile = blockIdx.x & 1;
        const size_t xtoff = (mat == 2) ? XT2o : XT1o;
        const int widx = (mat == 0) ? 0 : (mat == 1) ? 1 : 3;
        const float* bias = (mat == 0) ? bq1 : (mat == 1) ? bk : bq2;
        const float scale = (mat == 1) ? 1.0f : 0.0625f;
        u16* out = ws16 + ((mat == 0) ? Q1o : (mat == 1) ? Ko : Q2o);

        const u16* Ab = ws16 + xtoff + (size_t)m_tile * 128 * 256;
        const u16* Bb = ws16 + WBo + (size_t)widx * 65536 + (size_t)n_tile * 128 * 256;
        gemm_core(Ab, Bb, As, Bs, acc, tid);

        const int m0 = m_tile * 128;
        #pragma unroll
        for (int j = 0; j < 4; j++) {
            const int ncol = n_tile * 128 + wc * 64 + j * 16 + ln;
            const float bj = bias[ncol];
            #pragma unroll
            for (int i = 0; i < 4; i++) {
                const int mr = m0 + wr * 64 + i * 16 + quad * 4;
                #pragma unroll
                for (int r = 0; r < 4; r++)
                    out[(size_t)(mr + r) * 256 + ncol] =
                        f2b((acc[i * 4 + j][r] + bj) * scale);
            }
        }
    } else {
        const int b = blockIdx.x >> 4;
        const int o_tile = (blockIdx.x >> 3) & 1;
        const int p_tile = blockIdx.x & 7;
        const u16* Ab = ws16 + WBo + (size_t)2 * 65536 + (size_t)o_tile * 128 * 256;
        const u16* Bb = ws16 + XT1o + ((size_t)b * Pn + p_tile * 128) * 256;
        gemm_core(Ab, Bb, As, Bs, acc, tid);

        u16* vt = ws16 + VTo + (size_t)b * Cn * Pn;
        #pragma unroll
        for (int i = 0; i < 4; i++) {
            #pragma unroll
            for (int r = 0; r < 4; r++) {
                const int orow = o_tile * 128 + wr * 64 + i * 16 + quad * 4 + r;
                const float bo = bv[orow];
                #pragma unroll
                for (int j = 0; j < 4; j++) {
                    const int pcol = p_tile * 128 + wc * 64 + j * 16 + ln;
                    vt[(size_t)orow * Pn + pcol] = f2b(acc[i * 4 + j][r] + bo);
                }
            }
        }
    }
}

// ---------------------------------------------------------------------------
// attn v3 (R5-verified, unchanged): in-wave dual path, register K/V prefetch.
// block = 4 waves = 64 q-rows; 32 k-tokens per iter. grid (16, 32).
// ---------------------------------------------------------------------------
__global__ __launch_bounds__(256, 2) void attn_kernel(u16* __restrict__ ws16)
{
    const u16* Q1 = ws16 + Q1o;
    const u16* Kg = ws16 + Ko;
    const u16* Vt = ws16 + VTo;
    const u16* Q2 = ws16 + Q2o;

    __shared__ __align__(16) u16 Klds[32 * 256];    // [tok][c], chunk swizzle ^ (tok&7)
    __shared__ __align__(16) u16 Vtlds[256 * 32];   // [c][tok], chunk swizzle ^ (c&3)
    __shared__ __align__(16) u16 Plds[4 * 2 * 16 * 40];  // per-wave P1/P12, pad 40

    const int b    = blockIdx.y;
    const int q0   = blockIdx.x * 64;
    const int tid  = threadIdx.x;
    const int wid  = tid >> 6;
    const int lane = tid & 63;
    const int ln   = lane & 15;
    const int quad = lane >> 4;
    u16* Pw = Plds + wid * (2 * 16 * 40);

    const size_t qrow = (size_t)(b * Pn + q0 + wid * 16 + ln) * Cn;
    bf16x8 qa1[8], qa2[8];
    #pragma unroll
    for (int ch = 0; ch < 8; ch++) {
        qa1[ch] = *(const bf16x8*)&Q1[qrow + ch * 32 + quad * 8];
        qa2[ch] = *(const bf16x8*)&Q2[qrow + ch * 32 + quad * 8];
    }

    f32x4 acc1[16], acc12[16];
    #pragma unroll
    for (int t = 0; t < 16; t++) {
        acc1[t] = (f32x4){0.f, 0.f, 0.f, 0.f};
        acc12[t] = (f32x4){0.f, 0.f, 0.f, 0.f};
    }
    float lp1[4] = {}, lp12[4] = {};

    const int tokK = tid >> 3, giK = tid & 7;
    const int cbV = tid >> 2, gvV = tid & 3;
    u16x8 kpre[4], vpre[4];

    {
        const size_t growK = (size_t)(b * Pn + 0 + tokK) * Cn;
        #pragma unroll
        for (int i = 0; i < 4; i++)
            kpre[i] = *(const u16x8*)&Kg[growK + (size_t)(8 * i + (giK ^ (tokK & 7))) * 8];
        #pragma unroll
        for (int i = 0; i < 4; i++) {
            int cl = cbV + 64 * i;
            vpre[i] = *(const u16x8*)&Vt[((size_t)(b * Cn + cl)) * Pn + 0 + gvV * 8];
        }
    }

    for (int kt = 0; kt < 32; kt++) {
        __syncthreads();   // (A) all waves done reading LDS of prev iter

        #pragma unroll
        for (int i = 0; i < 4; i++)
            *(u16x8*)&Klds[tokK * 256 + (8 * i + giK) * 8] = kpre[i];
        #pragma unroll
        for (int i = 0; i < 4; i++) {
            int cl = cbV + 64 * i;
            int gp = gvV ^ (cl & 3);
            *(u16x8*)&Vtlds[cl * 32 + gp * 8] = vpre[i];
        }
        __syncthreads();   // (B) tile visible

        if (kt < 31) {
            const int k0n = (kt + 1) * 32;
            const size_t growK = (size_t)(b * Pn + k0n + tokK) * Cn;
            #pragma unroll
            for (int i = 0; i < 4; i++)
                kpre[i] = *(const u16x8*)&Kg[growK + (size_t)(8 * i + (giK ^ (tokK & 7))) * 8];
            #pragma unroll
            for (int i = 0; i < 4; i++) {
                int cl = cbV + 64 * i;
                vpre[i] = *(const u16x8*)&Vt[((size_t)(b * Cn + cl)) * Pn + k0n + gvV * 8];
            }
        }

        float s1v[2][4], s2v[2][4];
        #pragma unroll
        for (int st = 0; st < 2; st++) {
            f32x4 s1 = (f32x4){0.f, 0.f, 0.f, 0.f};
            f32x4 s2 = (f32x4){0.f, 0.f, 0.f, 0.f};
            #pragma unroll
            for (int ch = 0; ch < 8; ch++) {
                bf16x8 kb = *(const bf16x8*)
                    &Klds[(st * 16 + ln) * 256 + (((ch * 4 + quad) ^ (ln & 7))) * 8];
                s1 = __builtin_amdgcn_mfma_f32_16x16x32_bf16(qa1[ch], kb, s1, 0, 0, 0);
                s2 = __builtin_amdgcn_mfma_f32_16x16x32_bf16(qa2[ch], kb, s2, 0, 0, 0);
            }
            #pragma unroll
            for (int r = 0; r < 4; r++) { s1v[st][r] = s1[r]; s2v[st][r] = s2[r]; }
        }

        #pragma unroll
        for (int st = 0; st < 2; st++)
            #pragma unroll
            for (int r = 0; r < 4; r++) {
                float p1 = __expf(s1v[st][r]);
                float p12 = p1 * __expf(s2v[st][r]);
                lp1[r] += p1;
                lp12[r] += p12;
                int row = quad * 4 + r, col = st * 16 + ln;
                Pw[row * 40 + col]            = f2b(p1);
                Pw[16 * 40 + row * 40 + col]  = f2b(p12);
            }

        bf16x8 pa1 = *(const bf16x8*)&Pw[ln * 40 + quad * 8];
        bf16x8 pa2 = *(const bf16x8*)&Pw[16 * 40 + ln * 40 + quad * 8];
        #pragma unroll
        for (int t = 0; t < 16; t++) {
            bf16x8 vb = *(const bf16x8*)
                &Vtlds[(t * 16 + ln) * 32 + (quad ^ (ln & 3)) * 8];
            acc1[t]  = __builtin_amdgcn_mfma_f32_16x16x32_bf16(pa1, vb, acc1[t], 0, 0, 0);
            acc12[t] = __builtin_amdgcn_mfma_f32_16x16x32_bf16(pa2, vb, acc12[t], 0, 0, 0);
        }
    }

    u16* H1 = ws16 + H1o;
    u16* H12 = ws16 + H12o;
    #pragma unroll
    for (int r = 0; r < 4; r++) {
        float l1 = lp1[r], l2 = lp12[r];
        l1 += __shfl_xor(l1, 1); l2 += __shfl_xor(l2, 1);
        l1 += __shfl_xor(l1, 2); l2 += __shfl_xor(l2, 2);
        l1 += __shfl_xor(l1, 4); l2 += __shfl_xor(l2, 4);
        l1 += __shfl_xor(l1, 8); l2 += __shfl_xor(l2, 8);
        float i1 = 1.f / l1, i2 = 1.f / l2;
        size_t rowb = (size_t)(b * Pn + q0 + wid * 16 + quad * 4 + r) * Cn;
        #pragma unroll
        for (int t = 0; t < 16; t++) {
            H1[rowb + t * 16 + ln]  = f2b(acc1[t][r] * i1);
            H12[rowb + t * 16 + ln] = f2b(acc12[t][r] * i2);
        }
    }
}

// ---------------------------------------------------------------------------
// outproj: out[mat][b][o][p] = x1[b][o][p] + bias[o] + sum_c h[b][p][c]*w[o][c]
// grid (16, 64); block 256
// ---------------------------------------------------------------------------
__global__ __launch_bounds__(256) void outproj_kernel(
    const float* __restrict__ x1,
    const float* __restrict__ bps, const float* __restrict__ bpc,
    const u16* __restrict__ ws16, float* __restrict__ outp)
{
    __shared__ __align__(16) u16 As[128 * 64];
    __shared__ __align__(16) u16 Bs[128 * 64];
    const int tid = threadIdx.x;
    const int o_tile = blockIdx.x >> 3, p_tile = blockIdx.x & 7;
    const int mat = blockIdx.y >> 5, b = blockIdx.y & 31;
    const int wv = tid >> 6, lane = tid & 63;
    const int ln = lane & 15, quad = lane >> 4;
    const int wr = wv >> 1, wc = wv & 1;

    f32x4 acc[16];
    #pragma unroll
    for (int t = 0; t < 16; t++) acc[t] = (f32x4){0.f, 0.f, 0.f, 0.f};

    const u16* Ab = ws16 + WBo + (size_t)(4 + mat) * 65536 + (size_t)o_tile * 128 * 256;
    const u16* Bb = ws16 + (mat ? H12o : H1o) + ((size_t)b * Pn + p_tile * 128) * 256;
    gemm_core(Ab, Bb, As, Bs, acc, tid);

    const float* bias = mat ? bpc : bps;
    float* out = outp + (size_t)mat * Tn;
    #pragma unroll
    for (int i = 0; i < 4; i++) {
        #pragma unroll
        for (int r = 0; r < 4; r++) {
            const int orow = o_tile * 128 + wr * 64 + i * 16 + quad * 4 + r;
            const float bo = bias[orow];
            #pragma unroll
            for (int j = 0; j < 4; j++) {
                const int pcol = p_tile * 128 + wc * 64 + j * 16 + ln;
                const size_t idx = ((size_t)b * Cn + orow) * Pn + pcol;
                out[idx] = x1[idx] + bo + acc[i * 4 + j][r];
            }
        }
    }
}

// ---------------------------------------------------------------------------
extern "C" void kernel_launch(void* const* d_in, const int* in_sizes, int n_in,
                              void* d_out, int out_size, void* d_ws, size_t ws_size,
                              hipStream_t stream)
{
    const float* x1  = (const float*)d_in[0];
    const float* x2  = (const float*)d_in[1];
    const float* wq1 = (const float*)d_in[2];
    const float* bq1 = (const float*)d_in[3];
    const float* wk  = (const float*)d_in[4];
    const float* bk  = (const float*)d_in[5];
    const float* wv  = (const float*)d_in[6];
    const float* bv  = (const float*)d_in[7];
    const float* wq2 = (const float*)d_in[8];
    const float* bq2 = (const float*)d_in[9];
    const float* wps = (const float*)d_in[10];
    const float* bps = (const float*)d_in[11];
    const float* wpc = (const float*)d_in[12];
    const float* bpc = (const float*)d_in[13];
    float* out = (float*)d_out;
    u16* ws16 = (u16*)d_ws;

    cvt_kernel<<<dim3(16, 4, 70), 256, 0, stream>>>(
        x1, x2, wq1, wk, wv, wq2, wps, wpc, ws16);
    proj_kernel<<<dim3(512, 4), 256, 0, stream>>>(ws16, bq1, bk, bq2, bv);
    attn_kernel<<<dim3(Pn / 64, Bn), 256, 0, stream>>>(ws16);
    outproj_kernel<<<dim3(16, 64), 256, 0, stream>>>(x1, bps, bpc, ws16, out);
}